// Round 7
// baseline (344.221 us; speedup 1.0000x reference)
//
#include <hip/hip_runtime.h>
#include <hip/hip_bf16.h>
#include <math.h>

// Problem constants
#define BB 2
#define CC 512
#define HH 32
#define WW 32
#define HWP 1024      // H*W
#define GG 8
#define DH 64
#define HD 8
#define WD 8
#define JJ 64         // HD*WD
#define BG 16         // BB*GG
#define EPS 1e-5f

typedef __attribute__((ext_vector_type(8))) short short8;
typedef __attribute__((ext_vector_type(4))) short s16x4;
typedef __attribute__((ext_vector_type(4))) float f32x4;
typedef __attribute__((ext_vector_type(4))) unsigned short u16x4;
typedef __attribute__((ext_vector_type(4))) unsigned int u32x4;

// RNE float -> bf16 bits
static __device__ __forceinline__ short f2bf(float x) {
    unsigned u = __builtin_bit_cast(unsigned, x);
    u += 0x7FFFu + ((u >> 16) & 1u);
    return (short)(u >> 16);
}

// ---------------- K2: q grouped 1x1 conv via MFMA (BN1 folded in B-staging) ----------------
// grid: 256 blocks = bg(16) x i-tile(16); per-block 64(o) x 64(i), K=64.
__global__ __launch_bounds__(256) void k_qgemm(
    const float* __restrict__ x, const float* __restrict__ g1,
    const float* __restrict__ b1, const float* __restrict__ qw,
    float* __restrict__ q) {
    __shared__ __align__(16) short As[64][72];
    __shared__ __align__(16) short Bs[64][72];
    int blk = blockIdx.x;
    int bg = blk >> 4, nt = blk & 15;
    int b = bg >> 3, g = bg & 7;
    int i0 = nt * 64;
    int tid = threadIdx.x, lane = tid & 63, wv = tid >> 6;
    int wm = (wv >> 1) * 32, wn = (wv & 1) * 32;
    int l15 = lane & 15, quad = lane >> 4;
    const float invs = 1.0f / sqrtf(1.0f + EPS);
    // stage A: qw[g] 64x64 (row o, col c)
    {
        int c4 = (tid & 15) * 4;
        int ob = tid >> 4;
#pragma unroll
        for (int p = 0; p < 4; p++) {
            int o = ob + p * 16;
            f32x4 v = *(const f32x4*)(qw + (size_t)(g * 64 + o) * 64 + c4);
            s16x4 s = {f2bf(v.x), f2bf(v.y), f2bf(v.z), f2bf(v.w)};
            *(s16x4*)&As[o][c4] = s;
        }
    }
    // stage B: Bs[i][c] = bf16(BN1(x[b][g*64+c][i0+i]))
    {
        int i4 = (tid & 15) * 4;
        int cb = tid >> 4;
#pragma unroll
        for (int p = 0; p < 4; p++) {
            int c = cb + p * 16;
            f32x4 v = *(const f32x4*)(x + (size_t)(b * CC + g * 64 + c) * HWP + i0 + i4);
            float sc = g1[g * 64 + c] * invs;
            float sh = b1[g * 64 + c];
            Bs[i4 + 0][c] = f2bf(fmaf(v.x, sc, sh));
            Bs[i4 + 1][c] = f2bf(fmaf(v.y, sc, sh));
            Bs[i4 + 2][c] = f2bf(fmaf(v.z, sc, sh));
            Bs[i4 + 3][c] = f2bf(fmaf(v.w, sc, sh));
        }
    }
    __syncthreads();
    f32x4 acc[2][2];
#pragma unroll
    for (int a = 0; a < 2; a++)
#pragma unroll
        for (int c = 0; c < 2; c++) acc[a][c] = (f32x4){0.f, 0.f, 0.f, 0.f};
#pragma unroll
    for (int ks = 0; ks < 2; ks++) {
        short8 af0 = *(const short8*)&As[wm + l15][ks * 32 + quad * 8];
        short8 af1 = *(const short8*)&As[wm + 16 + l15][ks * 32 + quad * 8];
        short8 bf0 = *(const short8*)&Bs[wn + l15][ks * 32 + quad * 8];
        short8 bf1 = *(const short8*)&Bs[wn + 16 + l15][ks * 32 + quad * 8];
        acc[0][0] = __builtin_amdgcn_mfma_f32_16x16x32_bf16(af0, bf0, acc[0][0], 0, 0, 0);
        acc[0][1] = __builtin_amdgcn_mfma_f32_16x16x32_bf16(af0, bf1, acc[0][1], 0, 0, 0);
        acc[1][0] = __builtin_amdgcn_mfma_f32_16x16x32_bf16(af1, bf0, acc[1][0], 0, 0, 0);
        acc[1][1] = __builtin_amdgcn_mfma_f32_16x16x32_bf16(af1, bf1, acc[1][1], 0, 0, 0);
    }
#pragma unroll
    for (int im = 0; im < 2; im++)
#pragma unroll
        for (int r = 0; r < 4; r++) {
            int m = wm + im * 16 + quad * 4 + r;
#pragma unroll
            for (int in_ = 0; in_ < 2; in_++) {
                int n = wn + in_ * 16 + l15;
                q[(size_t)(bg * 64 + m) * HWP + i0 + n] = acc[im][in_][r];
            }
        }
}

// ---------------- K3: offsets -> vgrid ----------------
__global__ void k_off(const float* __restrict__ q, const float* __restrict__ dww,
                      const float* __restrict__ dwb, const float* __restrict__ pw,
                      float* __restrict__ vgrid) {
    int blk = blockIdx.x;          // bg*64 + hd*8 + wd
    int bg = blk >> 6;
    int hd = (blk >> 3) & 7;
    int wd = blk & 7;
    int ch = threadIdx.x;
    const float* qch = q + (size_t)(bg * 64 + ch) * HWP;
    float acc = 0.f;
#pragma unroll
    for (int kh = 0; kh < 6; kh++) {
        int hin = hd * 4 - 1 + kh;
        if (hin < 0 || hin >= HH) continue;
#pragma unroll
        for (int kw_ = 0; kw_ < 6; kw_++) {
            int win = wd * 4 - 1 + kw_;
            if (win < 0 || win >= WW) continue;
            acc = fmaf(qch[hin * WW + win], dww[ch * 36 + kh * 6 + kw_], acc);
        }
    }
    acc += dwb[ch];
    float ge = 0.5f * acc * (1.0f + erff(acc * 0.7071067811865475f));
    float p0 = ge * pw[ch];
    float p1 = ge * pw[64 + ch];
#pragma unroll
    for (int off = 32; off; off >>= 1) {
        p0 += __shfl_xor(p0, off);
        p1 += __shfl_xor(p1, off);
    }
    if (ch == 0) {
        float off0 = tanhf(p0) * 4.0f;
        float off1 = tanhf(p1) * 4.0f;
        float vx = (float)wd + off0;
        float vy = (float)hd + off1;
        float nx = 2.0f * vx / 7.0f - 1.0f;
        float ny = 2.0f * vy / 7.0f - 1.0f;
        vgrid[blk * 2] = nx;
        vgrid[blk * 2 + 1] = ny;
    }
}

// ---------------- K4+K5 fused: grid_sample (BN1 folded) + k/v grouped conv ----------------
// grid: 1024 blocks = bg*64 + j; 64 threads (ch for sampling, o for conv).
__global__ __launch_bounds__(64) void k_skv(
    const float* __restrict__ x, const float* __restrict__ g1,
    const float* __restrict__ b1, const float* __restrict__ vgrid,
    const float* __restrict__ kw, const float* __restrict__ vw,
    float* __restrict__ kk, float* __restrict__ vv) {
    __shared__ float sm[64];
    int blk = blockIdx.x;          // bg*64 + j
    int bg = blk >> 6, j = blk & 63;
    int g = bg & 7, b = bg >> 3;
    int t = threadIdx.x;
    const float invs = 1.0f / sqrtf(1.0f + EPS);
    {
        int cg = g * 64 + t;
        float s = g1[cg] * invs;
        float bv = b1[cg];
        float nx = vgrid[blk * 2];
        float ny = vgrid[blk * 2 + 1];
        float gx = (nx + 1.0f) * 16.0f - 0.5f;
        float gy = (ny + 1.0f) * 16.0f - 0.5f;
        float x0f = floorf(gx), y0f = floorf(gy);
        float wx = gx - x0f, wy = gy - y0f;
        int x0 = (int)x0f, y0 = (int)y0f;
        const float* im = x + (size_t)(b * CC + cg) * HWP;
        float sx = 0.f, sw = 0.f;
        float w00 = (1 - wx) * (1 - wy), w01 = wx * (1 - wy);
        float w10 = (1 - wx) * wy, w11 = wx * wy;
        if (x0 >= 0 && x0 < WW && y0 >= 0 && y0 < HH)                 { sx += w00 * im[y0 * WW + x0];           sw += w00; }
        if (x0 + 1 >= 0 && x0 + 1 < WW && y0 >= 0 && y0 < HH)         { sx += w01 * im[y0 * WW + x0 + 1];       sw += w01; }
        if (x0 >= 0 && x0 < WW && y0 + 1 >= 0 && y0 + 1 < HH)         { sx += w10 * im[(y0 + 1) * WW + x0];     sw += w10; }
        if (x0 + 1 >= 0 && x0 + 1 < WW && y0 + 1 >= 0 && y0 + 1 < HH) { sx += w11 * im[(y0 + 1) * WW + x0 + 1]; sw += w11; }
        sm[t] = s * sx + bv * sw;
    }
    __syncthreads();
    const float* kwr = kw + (size_t)(g * 64 + t) * 64;
    const float* vwr = vw + (size_t)(g * 64 + t) * 64;
    float ak = 0.f, av = 0.f;
#pragma unroll
    for (int c = 0; c < 64; c++) {
        float tv = sm[c];
        ak = fmaf(tv, kwr[c], ak);
        av = fmaf(tv, vwr[c], av);
    }
    kk[(size_t)bg * 4096 + j * 64 + t] = ak;
    vv[(size_t)bg * 4096 + j * 64 + t] = av;
}

// ---------------- K5b: pre-pack W2 into bf16 fragment order ----------------
__global__ void k_w2pack(const float* __restrict__ w2, unsigned short* __restrict__ w2p) {
    int idx = blockIdx.x * 256 + threadIdx.x;   // 16384
    int k = idx >> 7, n = idx & 127;
    int dest = ((((n >> 4) * 4 + (k >> 5)) * 64) + (((k >> 3) & 3) * 16) + (n & 15)) * 8 + (k & 7);
    w2p[dest] = (unsigned short)f2bf(w2[idx]);
}

// ---------------- K6: CPB bias MLP via bf16 MFMA (v4: LDS = exactly 32KB -> 5 blocks/CU) ----------------
// Coefs read from global (quad-uniform b128, L1-resident).
__global__ __launch_bounds__(256, 5) void k_cpb(
    const float* __restrict__ vgrid, const unsigned short* __restrict__ w2p,
    const float* __restrict__ w1, const float* __restrict__ b1,
    const float* __restrict__ b2, const float* __restrict__ w3,
    const float* __restrict__ b3, float* __restrict__ bias) {
    __shared__ __align__(16) short w2fs[16384];   // exactly 32768 B
    int tid = threadIdx.x;
    {
        const u32x4* src = (const u32x4*)w2p;
        u32x4* dst = (u32x4*)w2fs;
        for (int c = tid; c < 2048; c += 256) dst[c] = src[c];
    }
    float bias3 = b3[0];
    __syncthreads();

    int lane = tid & 63;
    int wv = tid >> 6;
    int l15 = lane & 15;
    int quad = lane >> 4;

#pragma unroll 1
    for (int it = 0; it < 4; it++) {
        int p = (blockIdx.x * 4 + it) * 4 + wv;
        int bg = p >> 11;
        int i = (p >> 1) & 1023;
        int jbase = (p & 1) * 32;
        int hi = i >> 5, wi = i & 31;
        float qx = 2.0f * (float)wi / 31.0f - 1.0f;
        float qy = 2.0f * (float)hi / 31.0f - 1.0f;

        int jA = jbase + l15;
        float gkxA = vgrid[(bg * 64 + jA) * 2];
        float gkyA = vgrid[(bg * 64 + jA) * 2 + 1];
        float gkxB = vgrid[(bg * 64 + jA + 16) * 2];
        float gkyB = vgrid[(bg * 64 + jA + 16) * 2 + 1];
        float p0 = qx - gkxA, p1 = qy - gkyA;
        float s0a = copysignf(log1pf(fabsf(p0)), p0);
        float s1a = copysignf(log1pf(fabsf(p1)), p1);
        p0 = qx - gkxB; p1 = qy - gkyB;
        float s0b = copysignf(log1pf(fabsf(p0)), p0);
        float s1b = copysignf(log1pf(fabsf(p1)), p1);

        short8 hA[4], hB[4];
#pragma unroll
        for (int kc = 0; kc < 4; kc++) {
            f32x4 cu0 = *(const f32x4*)(w1 + kc * 32 + quad * 8);
            f32x4 cu1 = *(const f32x4*)(w1 + kc * 32 + quad * 8 + 4);
            f32x4 cv0 = *(const f32x4*)(w1 + 128 + kc * 32 + quad * 8);
            f32x4 cv1 = *(const f32x4*)(w1 + 128 + kc * 32 + quad * 8 + 4);
            f32x4 cb0 = *(const f32x4*)(b1 + kc * 32 + quad * 8);
            f32x4 cb1 = *(const f32x4*)(b1 + kc * 32 + quad * 8 + 4);
            u32x4 pa, pb;
#pragma unroll
            for (int j2 = 0; j2 < 4; j2++) {
                int e0 = 2 * j2, e1 = 2 * j2 + 1;
                float u0 = (e0 < 4) ? cu0[e0] : cu1[e0 - 4];
                float u1 = (e1 < 4) ? cu0[e1] : cu1[e1 - 4];
                float v0 = (e0 < 4) ? cv0[e0] : cv1[e0 - 4];
                float v1 = (e1 < 4) ? cv0[e1] : cv1[e1 - 4];
                float c0 = (e0 < 4) ? cb0[e0] : cb1[e0 - 4];
                float c1 = (e1 < 4) ? cb0[e1] : cb1[e1 - 4];
                unsigned a0 = __builtin_bit_cast(unsigned,
                    fmaxf(fmaf(s0a, u0, fmaf(s1a, v0, c0)), 0.f)) + 0x8000u;
                unsigned a1 = __builtin_bit_cast(unsigned,
                    fmaxf(fmaf(s0a, u1, fmaf(s1a, v1, c1)), 0.f)) + 0x8000u;
                pa[j2] = __builtin_amdgcn_perm(a1, a0, 0x07060302);
                unsigned b0 = __builtin_bit_cast(unsigned,
                    fmaxf(fmaf(s0b, u0, fmaf(s1b, v0, c0)), 0.f)) + 0x8000u;
                unsigned b1_ = __builtin_bit_cast(unsigned,
                    fmaxf(fmaf(s0b, u1, fmaf(s1b, v1, c1)), 0.f)) + 0x8000u;
                pb[j2] = __builtin_amdgcn_perm(b1_, b0, 0x07060302);
            }
            hA[kc] = __builtin_bit_cast(short8, pa);
            hB[kc] = __builtin_bit_cast(short8, pb);
        }

        float psumA = 0.f, psumB = 0.f;
#pragma unroll 1
        for (int nt = 0; nt < 8; nt++) {
            f32x4 accA = (f32x4){0.f, 0.f, 0.f, 0.f};
            f32x4 accB = (f32x4){0.f, 0.f, 0.f, 0.f};
#pragma unroll
            for (int kc = 0; kc < 4; kc++) {
                short8 af = *(const short8*)(w2fs + (((nt * 4 + kc) * 64) + lane) * 8);
                accA = __builtin_amdgcn_mfma_f32_16x16x32_bf16(af, hA[kc], accA, 0, 0, 0);
                accB = __builtin_amdgcn_mfma_f32_16x16x32_bf16(af, hB[kc], accB, 0, 0, 0);
            }
            f32x4 b2q = *(const f32x4*)(b2 + nt * 16 + quad * 4);
            f32x4 w3q = *(const f32x4*)(w3 + nt * 16 + quad * 4);
#pragma unroll
            for (int r = 0; r < 4; r++) {
                psumA = fmaf(fmaxf(accA[r] + b2q[r], 0.f), w3q[r], psumA);
                psumB = fmaf(fmaxf(accB[r] + b2q[r], 0.f), w3q[r], psumB);
            }
        }
        psumA += __shfl_xor(psumA, 16);
        psumA += __shfl_xor(psumA, 32);
        psumB += __shfl_xor(psumB, 16);
        psumB += __shfl_xor(psumB, 32);
        if (quad == 0) {
            bias[(size_t)(p * 2 + 0) * 16 + l15] = psumA + bias3;
            bias[(size_t)(p * 2 + 1) * 16 + l15] = psumB + bias3;
        }
    }
}

// ---------------- K7: attention via MFMA (flash-style, coalesced O store) ----------------
__global__ __launch_bounds__(256) void k_attn(
    const float* __restrict__ q, const float* __restrict__ kk,
    const float* __restrict__ vv, const float* __restrict__ bias,
    unsigned short* __restrict__ ao) {
    __shared__ __align__(16) short Ks[64][72];    // [j][d] bf16
    __shared__ __align__(16) short Vt[64][72];    // [d][j] bf16
    __shared__ __align__(16) short Qs[64][72];    // [i][d] bf16; reused as Ot[d][i]
    __shared__ __align__(16) short Ps[4][16][72]; // per-wave P
    int blk = blockIdx.x;
    int bg = blk >> 4;
    int chunk = blk & 15;
    int i0 = chunk * 64;
    int b = bg >> 3, g = bg & 7;
    int tid = threadIdx.x, lane = tid & 63, wv = tid >> 6;
    int l15 = lane & 15, quad = lane >> 4;

    const float* kbase = kk + (size_t)bg * 4096;
    const float* vbase = vv + (size_t)bg * 4096;
#pragma unroll
    for (int it = 0; it < 4; it++) {
        int e4 = it * 1024 + tid * 4;
        int j = e4 >> 6, d = e4 & 63;
        f32x4 k4 = *(const f32x4*)(kbase + e4);
        s16x4 s = {f2bf(k4.x), f2bf(k4.y), f2bf(k4.z), f2bf(k4.w)};
        *(s16x4*)&Ks[j][d] = s;
        f32x4 v4 = *(const f32x4*)(vbase + e4);
        Vt[d + 0][j] = f2bf(v4.x);
        Vt[d + 1][j] = f2bf(v4.y);
        Vt[d + 2][j] = f2bf(v4.z);
        Vt[d + 3][j] = f2bf(v4.w);
    }
    const float* qbase = q + (size_t)(b * CC + g * 64) * HWP + i0;
#pragma unroll
    for (int it = 0; it < 4; it++) {
        int e4 = it * 1024 + tid * 4;
        int d = e4 >> 6, i = e4 & 63;
        f32x4 q4 = *(const f32x4*)(qbase + (size_t)d * HWP + i);
        Qs[i + 0][d] = f2bf(q4.x * 0.125f);
        Qs[i + 1][d] = f2bf(q4.y * 0.125f);
        Qs[i + 2][d] = f2bf(q4.z * 0.125f);
        Qs[i + 3][d] = f2bf(q4.w * 0.125f);
    }
    __syncthreads();

    int iw = wv * 16;
    f32x4 Sacc[4];
#pragma unroll
    for (int nt = 0; nt < 4; nt++) Sacc[nt] = (f32x4){0.f, 0.f, 0.f, 0.f};
#pragma unroll
    for (int ks = 0; ks < 2; ks++) {
        short8 aq = *(const short8*)&Qs[iw + l15][quad * 8 + ks * 32];
#pragma unroll
        for (int nt = 0; nt < 4; nt++) {
            short8 bk = *(const short8*)&Ks[nt * 16 + l15][quad * 8 + ks * 32];
            Sacc[nt] = __builtin_amdgcn_mfma_f32_16x16x32_bf16(aq, bk, Sacc[nt], 0, 0, 0);
        }
    }
    const float* bp = bias + ((size_t)bg * 1024 + i0 + iw + quad * 4) * 64 + l15;
    float Sv[4][4];
#pragma unroll
    for (int nt = 0; nt < 4; nt++)
#pragma unroll
        for (int r = 0; r < 4; r++)
            Sv[nt][r] = Sacc[nt][r] + bp[r * 64 + nt * 16];
#pragma unroll
    for (int r = 0; r < 4; r++) {
        float m = fmaxf(fmaxf(Sv[0][r], Sv[1][r]), fmaxf(Sv[2][r], Sv[3][r]));
        m = fmaxf(m, __shfl_xor(m, 1));
        m = fmaxf(m, __shfl_xor(m, 2));
        m = fmaxf(m, __shfl_xor(m, 4));
        m = fmaxf(m, __shfl_xor(m, 8));
        float l = 0.f;
#pragma unroll
        for (int nt = 0; nt < 4; nt++) { Sv[nt][r] = expf(Sv[nt][r] - m); l += Sv[nt][r]; }
        l += __shfl_xor(l, 1);
        l += __shfl_xor(l, 2);
        l += __shfl_xor(l, 4);
        l += __shfl_xor(l, 8);
        float inv = 1.0f / l;
#pragma unroll
        for (int nt = 0; nt < 4; nt++)
            Ps[wv][quad * 4 + r][nt * 16 + l15] = f2bf(Sv[nt][r] * inv);
    }
    f32x4 Oacc[4];
#pragma unroll
    for (int nt = 0; nt < 4; nt++) Oacc[nt] = (f32x4){0.f, 0.f, 0.f, 0.f};
#pragma unroll
    for (int ks = 0; ks < 2; ks++) {
        short8 ap = *(const short8*)&Ps[wv][l15][quad * 8 + ks * 32];
#pragma unroll
        for (int nt = 0; nt < 4; nt++) {
            short8 bv = *(const short8*)&Vt[nt * 16 + l15][quad * 8 + ks * 32];
            Oacc[nt] = __builtin_amdgcn_mfma_f32_16x16x32_bf16(ap, bv, Oacc[nt], 0, 0, 0);
        }
    }
    // bounce O through LDS (reuse Qs as Ot[d][i_local]) for coalesced bf16 stores
    __syncthreads();   // all waves done reading Qs
#pragma unroll
    for (int nt = 0; nt < 4; nt++) {
        s16x4 o4 = {f2bf(Oacc[nt][0]), f2bf(Oacc[nt][1]), f2bf(Oacc[nt][2]), f2bf(Oacc[nt][3])};
        *(s16x4*)&Qs[nt * 16 + l15][iw + quad * 4] = o4;
    }
    __syncthreads();
    {
        int d = tid >> 2;
        int ic = (tid & 3) * 16;
        short8 a = *(const short8*)&Qs[d][ic];
        short8 c = *(const short8*)&Qs[d][ic + 8];
        unsigned short* dst = ao + (size_t)(b * CC + g * 64 + d) * HWP + i0 + ic;
        *(short8*)dst = a;
        *(short8*)(dst + 8) = c;
    }
}

// ---------------- K8/K10/K11: tiled bf16-MFMA GEMM ----------------
template<int EPI, int KD, int MT, bool BBF, bool BN>
__global__ __launch_bounds__(256) void k_gemm(
    const float* __restrict__ A, const void* __restrict__ Bp,
    const float* __restrict__ resid, const float* __restrict__ bias,
    void* __restrict__ outp,
    const float* __restrict__ bns, const float* __restrict__ bnb) {
    constexpr int MM = MT * 64;
    __shared__ __align__(16) short As[64][72];
    __shared__ __align__(16) short Bs[64][72];
    int tid = threadIdx.x;
    int blk = blockIdx.x;
    int mt = blk & (MT - 1);
    int nb = blk / MT;              // 0..31
    int bb = nb >> 4, nt = nb & 15;
    int m0 = mt * 64, i0 = nt * 64;
    int lane = tid & 63, wv = tid >> 6;
    int wm = (wv >> 1) * 32, wn = (wv & 1) * 32;
    int l15 = lane & 15, quad = lane >> 4;
    const float* Af = A + (size_t)m0 * KD;
    const float* Bf = (const float*)Bp;
    const unsigned short* Bh = (const unsigned short*)Bp;
    const float invs = 1.0f / sqrtf(1.0f + EPS);

    f32x4 acc[2][2];
#pragma unroll
    for (int a = 0; a < 2; a++)
#pragma unroll
        for (int c = 0; c < 2; c++) acc[a][c] = (f32x4){0.f, 0.f, 0.f, 0.f};

    for (int k0 = 0; k0 < KD; k0 += 64) {
        __syncthreads();
        {
            int kk4 = (tid & 15) * 4;
            int myb = tid >> 4;
#pragma unroll
            for (int p = 0; p < 4; p++) {
                int my = myb + p * 16;
                f32x4 v = *(const f32x4*)(Af + (size_t)my * KD + k0 + kk4);
                s16x4 s = {f2bf(v.x), f2bf(v.y), f2bf(v.z), f2bf(v.w)};
                *(s16x4*)&As[my][kk4] = s;
            }
        }
        {
            int i4 = (tid & 15) * 4;
            int kyb = tid >> 4;
#pragma unroll
            for (int p = 0; p < 4; p++) {
                int ky = kyb + p * 16;
                size_t goff = (size_t)bb * KD * HWP + (size_t)(k0 + ky) * HWP + i0 + i4;
                if (BBF) {
                    u16x4 v = *(const u16x4*)(Bh + goff);
                    Bs[i4 + 0][ky] = (short)v.x;
                    Bs[i4 + 1][ky] = (short)v.y;
                    Bs[i4 + 2][ky] = (short)v.z;
                    Bs[i4 + 3][ky] = (short)v.w;
                } else {
                    f32x4 v = *(const f32x4*)(Bf + goff);
                    if (BN) {
                        float sc = bns[k0 + ky] * invs;
                        float sh = bnb[k0 + ky];
                        v.x = fmaf(v.x, sc, sh);
                        v.y = fmaf(v.y, sc, sh);
                        v.z = fmaf(v.z, sc, sh);
                        v.w = fmaf(v.w, sc, sh);
                    }
                    Bs[i4 + 0][ky] = f2bf(v.x);
                    Bs[i4 + 1][ky] = f2bf(v.y);
                    Bs[i4 + 2][ky] = f2bf(v.z);
                    Bs[i4 + 3][ky] = f2bf(v.w);
                }
            }
        }
        __syncthreads();
#pragma unroll
        for (int ks = 0; ks < 2; ks++) {
            short8 af0 = *(const short8*)&As[wm + l15][ks * 32 + quad * 8];
            short8 af1 = *(const short8*)&As[wm + 16 + l15][ks * 32 + quad * 8];
            short8 bf0 = *(const short8*)&Bs[wn + l15][ks * 32 + quad * 8];
            short8 bf1 = *(const short8*)&Bs[wn + 16 + l15][ks * 32 + quad * 8];
            acc[0][0] = __builtin_amdgcn_mfma_f32_16x16x32_bf16(af0, bf0, acc[0][0], 0, 0, 0);
            acc[0][1] = __builtin_amdgcn_mfma_f32_16x16x32_bf16(af0, bf1, acc[0][1], 0, 0, 0);
            acc[1][0] = __builtin_amdgcn_mfma_f32_16x16x32_bf16(af1, bf0, acc[1][0], 0, 0, 0);
            acc[1][1] = __builtin_amdgcn_mfma_f32_16x16x32_bf16(af1, bf1, acc[1][1], 0, 0, 0);
        }
    }

    float* outF = (float*)outp;
    unsigned short* outH = (unsigned short*)outp;
#pragma unroll
    for (int im = 0; im < 2; im++) {
#pragma unroll
        for (int r = 0; r < 4; r++) {
            int m = m0 + wm + im * 16 + quad * 4 + r;
            float bv = bias[m];
#pragma unroll
            for (int in_ = 0; in_ < 2; in_++) {
                int n = i0 + wn + in_ * 16 + l15;
                size_t idx = ((size_t)bb * MM + m) * HWP + n;
                float v = acc[im][in_][r] + bv;
                if constexpr (EPI == 1) {
                    float ge = 0.5f * v * (1.0f + erff(v * 0.7071067811865475f));
                    outH[idx] = (unsigned short)f2bf(ge);
                } else {
                    outF[idx] = v + resid[idx];
                }
            }
        }
    }
}

extern "C" void kernel_launch(void* const* d_in, const int* in_sizes, int n_in,
                              void* d_out, int out_size, void* d_ws, size_t ws_size,
                              hipStream_t stream) {
    const float* x      = (const float*)d_in[0];
    const float* bn1_g  = (const float*)d_in[1];
    const float* bn1_b  = (const float*)d_in[2];
    const float* bn2_g  = (const float*)d_in[3];
    const float* bn2_b  = (const float*)d_in[4];
    const float* qw     = (const float*)d_in[5];
    const float* kw     = (const float*)d_in[6];
    const float* vw     = (const float*)d_in[7];
    const float* out_w  = (const float*)d_in[8];
    const float* out_b  = (const float*)d_in[9];
    const float* off_dw_w = (const float*)d_in[10];
    const float* off_dw_b = (const float*)d_in[11];
    const float* off_pw_w = (const float*)d_in[12];
    const float* cpb_w1 = (const float*)d_in[13];
    const float* cpb_b1 = (const float*)d_in[14];
    const float* cpb_w2 = (const float*)d_in[15];
    const float* cpb_b2 = (const float*)d_in[16];
    const float* cpb_w3 = (const float*)d_in[17];
    const float* cpb_b3 = (const float*)d_in[18];
    const float* mlp_w1 = (const float*)d_in[19];
    const float* mlp_b1 = (const float*)d_in[20];
    const float* mlp_w2 = (const float*)d_in[21];
    const float* mlp_b2 = (const float*)d_in[22];

    float* ws = (float*)d_ws;
    float* q     = ws + 1048576;      // 1,048,576
    float* vgrid = ws + 2097152;      // 2,048
    float* kk    = ws + 2164736;      // 65,536
    float* vv    = ws + 2230272;      // 65,536
    unsigned short* w2p = (unsigned short*)(ws + 2295808);  // 16,384 bf16
    unsigned short* ao  = (unsigned short*)(ws + 2312192);  // 1,048,576 bf16
    float* xo    = ws + 3360768;      // 1,048,576
    float* h1of  = ws + 4409344;      // bias (1M floats), then h1o bf16 (4M)
    float* biasb = h1of;
    unsigned short* h1o = (unsigned short*)h1of;

    hipLaunchKernelGGL(k_qgemm, dim3(256), dim3(256), 0, stream, x, bn1_g, bn1_b, qw, q);
    hipLaunchKernelGGL(k_off, dim3(1024), dim3(64), 0, stream, q, off_dw_w, off_dw_b, off_pw_w, vgrid);
    hipLaunchKernelGGL(k_skv, dim3(1024), dim3(64), 0, stream, x, bn1_g, bn1_b, vgrid, kw, vw, kk, vv);
    hipLaunchKernelGGL(k_w2pack, dim3(64), dim3(256), 0, stream, cpb_w2, w2p);
    hipLaunchKernelGGL(k_cpb, dim3(2048), dim3(256), 0, stream,
                       vgrid, w2p, cpb_w1, cpb_b1, cpb_b2, cpb_w3, cpb_b3, biasb);
    hipLaunchKernelGGL(k_attn, dim3(256), dim3(256), 0, stream, q, kk, vv, biasb, ao);
    k_gemm<0, 512, 8, true, false><<<dim3(256), dim3(256), 0, stream>>>(
        out_w, ao, x, out_b, xo, nullptr, nullptr);
    k_gemm<1, 512, 32, false, true><<<dim3(1024), dim3(256), 0, stream>>>(
        mlp_w1, xo, nullptr, mlp_b1, h1o, bn2_g, bn2_b);
    k_gemm<2, 2048, 8, true, false><<<dim3(256), dim3(256), 0, stream>>>(
        mlp_w2, h1o, xo, mlp_b2, d_out, nullptr, nullptr);
}

// Round 8
// 284.549 us; speedup vs baseline: 1.2097x; 1.2097x over previous
//
#include <hip/hip_runtime.h>
#include <hip/hip_bf16.h>
#include <math.h>

// Problem constants
#define BB 2
#define CC 512
#define HH 32
#define WW 32
#define HWP 1024      // H*W
#define GG 8
#define DH 64
#define HD 8
#define WD 8
#define JJ 64         // HD*WD
#define BG 16         // BB*GG
#define EPS 1e-5f

typedef __attribute__((ext_vector_type(8))) short short8;
typedef __attribute__((ext_vector_type(4))) short s16x4;
typedef __attribute__((ext_vector_type(4))) float f32x4;
typedef __attribute__((ext_vector_type(4))) unsigned short u16x4;
typedef __attribute__((ext_vector_type(4))) unsigned int u32x4;

// RNE float -> bf16 bits
static __device__ __forceinline__ short f2bf(float x) {
    unsigned u = __builtin_bit_cast(unsigned, x);
    u += 0x7FFFu + ((u >> 16) & 1u);
    return (short)(u >> 16);
}

// ---------------- K0: pre-pack GEMM weights to bf16 (qw | out_w | mlp_w1 | mlp_w2) ----------------
// sizes: 32768 | 262144 | 1048576 | 1048576 -> 2,392,064 elements, contiguous in wp.
__global__ void k_wpack(const float* __restrict__ qw, const float* __restrict__ ow,
                        const float* __restrict__ w1, const float* __restrict__ w2,
                        unsigned short* __restrict__ wp) {
    int idx = blockIdx.x * 256 + threadIdx.x;
    float v;
    if (idx < 32768) v = qw[idx];
    else if (idx < 294912) v = ow[idx - 32768];
    else if (idx < 1343488) v = w1[idx - 294912];
    else v = w2[idx - 1343488];
    wp[idx] = (unsigned short)f2bf(v);
}

// ---------------- K2: q grouped 1x1 conv via MFMA (BN1 folded in B-staging) ----------------
// grid: 256 blocks = bg(16) x i-tile(16); per-block 64(o) x 64(i), K=64.
__global__ __launch_bounds__(256) void k_qgemm(
    const float* __restrict__ x, const float* __restrict__ g1,
    const float* __restrict__ b1, const unsigned short* __restrict__ qwp,
    float* __restrict__ q) {
    __shared__ __align__(16) short As[64][72];
    __shared__ __align__(16) short Bs[64][72];
    int blk = blockIdx.x;
    int bg = blk >> 4, nt = blk & 15;
    int b = bg >> 3, g = bg & 7;
    int i0 = nt * 64;
    int tid = threadIdx.x, lane = tid & 63, wv = tid >> 6;
    int wm = (wv >> 1) * 32, wn = (wv & 1) * 32;
    int l15 = lane & 15, quad = lane >> 4;
    const float invs = 1.0f / sqrtf(1.0f + EPS);
    // stage A: qw[g] 64x64 (row o, col c), prepacked bf16
    {
        int c4 = (tid & 15) * 4;
        int ob = tid >> 4;
#pragma unroll
        for (int p = 0; p < 4; p++) {
            int o = ob + p * 16;
            u16x4 v = *(const u16x4*)(qwp + (size_t)(g * 64 + o) * 64 + c4);
            *(u16x4*)&As[o][c4] = v;
        }
    }
    // stage B: Bs[i][c] = bf16(BN1(x[b][g*64+c][i0+i]))
    {
        int i4 = (tid & 15) * 4;
        int cb = tid >> 4;
#pragma unroll
        for (int p = 0; p < 4; p++) {
            int c = cb + p * 16;
            f32x4 v = *(const f32x4*)(x + (size_t)(b * CC + g * 64 + c) * HWP + i0 + i4);
            float sc = g1[g * 64 + c] * invs;
            float sh = b1[g * 64 + c];
            Bs[i4 + 0][c] = f2bf(fmaf(v.x, sc, sh));
            Bs[i4 + 1][c] = f2bf(fmaf(v.y, sc, sh));
            Bs[i4 + 2][c] = f2bf(fmaf(v.z, sc, sh));
            Bs[i4 + 3][c] = f2bf(fmaf(v.w, sc, sh));
        }
    }
    __syncthreads();
    f32x4 acc[2][2];
#pragma unroll
    for (int a = 0; a < 2; a++)
#pragma unroll
        for (int c = 0; c < 2; c++) acc[a][c] = (f32x4){0.f, 0.f, 0.f, 0.f};
#pragma unroll
    for (int ks = 0; ks < 2; ks++) {
        short8 af0 = *(const short8*)&As[wm + l15][ks * 32 + quad * 8];
        short8 af1 = *(const short8*)&As[wm + 16 + l15][ks * 32 + quad * 8];
        short8 bf0 = *(const short8*)&Bs[wn + l15][ks * 32 + quad * 8];
        short8 bf1 = *(const short8*)&Bs[wn + 16 + l15][ks * 32 + quad * 8];
        acc[0][0] = __builtin_amdgcn_mfma_f32_16x16x32_bf16(af0, bf0, acc[0][0], 0, 0, 0);
        acc[0][1] = __builtin_amdgcn_mfma_f32_16x16x32_bf16(af0, bf1, acc[0][1], 0, 0, 0);
        acc[1][0] = __builtin_amdgcn_mfma_f32_16x16x32_bf16(af1, bf0, acc[1][0], 0, 0, 0);
        acc[1][1] = __builtin_amdgcn_mfma_f32_16x16x32_bf16(af1, bf1, acc[1][1], 0, 0, 0);
    }
#pragma unroll
    for (int im = 0; im < 2; im++)
#pragma unroll
        for (int r = 0; r < 4; r++) {
            int m = wm + im * 16 + quad * 4 + r;
#pragma unroll
            for (int in_ = 0; in_ < 2; in_++) {
                int n = wn + in_ * 16 + l15;
                q[(size_t)(bg * 64 + m) * HWP + i0 + n] = acc[im][in_][r];
            }
        }
}

// ---------------- K3: offsets -> vgrid ----------------
__global__ void k_off(const float* __restrict__ q, const float* __restrict__ dww,
                      const float* __restrict__ dwb, const float* __restrict__ pw,
                      float* __restrict__ vgrid) {
    int blk = blockIdx.x;          // bg*64 + hd*8 + wd
    int bg = blk >> 6;
    int hd = (blk >> 3) & 7;
    int wd = blk & 7;
    int ch = threadIdx.x;
    const float* qch = q + (size_t)(bg * 64 + ch) * HWP;
    float acc = 0.f;
#pragma unroll
    for (int kh = 0; kh < 6; kh++) {
        int hin = hd * 4 - 1 + kh;
        if (hin < 0 || hin >= HH) continue;
#pragma unroll
        for (int kw_ = 0; kw_ < 6; kw_++) {
            int win = wd * 4 - 1 + kw_;
            if (win < 0 || win >= WW) continue;
            acc = fmaf(qch[hin * WW + win], dww[ch * 36 + kh * 6 + kw_], acc);
        }
    }
    acc += dwb[ch];
    float ge = 0.5f * acc * (1.0f + erff(acc * 0.7071067811865475f));
    float p0 = ge * pw[ch];
    float p1 = ge * pw[64 + ch];
#pragma unroll
    for (int off = 32; off; off >>= 1) {
        p0 += __shfl_xor(p0, off);
        p1 += __shfl_xor(p1, off);
    }
    if (ch == 0) {
        float off0 = tanhf(p0) * 4.0f;
        float off1 = tanhf(p1) * 4.0f;
        float vx = (float)wd + off0;
        float vy = (float)hd + off1;
        float nx = 2.0f * vx / 7.0f - 1.0f;
        float ny = 2.0f * vy / 7.0f - 1.0f;
        vgrid[blk * 2] = nx;
        vgrid[blk * 2 + 1] = ny;
    }
}

// ---------------- K4+K5 fused: grid_sample (BN1 folded) + k/v grouped conv ----------------
__global__ __launch_bounds__(64) void k_skv(
    const float* __restrict__ x, const float* __restrict__ g1,
    const float* __restrict__ b1, const float* __restrict__ vgrid,
    const float* __restrict__ kw, const float* __restrict__ vw,
    float* __restrict__ kk, float* __restrict__ vv) {
    __shared__ float sm[64];
    int blk = blockIdx.x;          // bg*64 + j
    int bg = blk >> 6, j = blk & 63;
    int g = bg & 7, b = bg >> 3;
    int t = threadIdx.x;
    const float invs = 1.0f / sqrtf(1.0f + EPS);
    {
        int cg = g * 64 + t;
        float s = g1[cg] * invs;
        float bv = b1[cg];
        float nx = vgrid[blk * 2];
        float ny = vgrid[blk * 2 + 1];
        float gx = (nx + 1.0f) * 16.0f - 0.5f;
        float gy = (ny + 1.0f) * 16.0f - 0.5f;
        float x0f = floorf(gx), y0f = floorf(gy);
        float wx = gx - x0f, wy = gy - y0f;
        int x0 = (int)x0f, y0 = (int)y0f;
        const float* im = x + (size_t)(b * CC + cg) * HWP;
        float sx = 0.f, sw = 0.f;
        float w00 = (1 - wx) * (1 - wy), w01 = wx * (1 - wy);
        float w10 = (1 - wx) * wy, w11 = wx * wy;
        if (x0 >= 0 && x0 < WW && y0 >= 0 && y0 < HH)                 { sx += w00 * im[y0 * WW + x0];           sw += w00; }
        if (x0 + 1 >= 0 && x0 + 1 < WW && y0 >= 0 && y0 < HH)         { sx += w01 * im[y0 * WW + x0 + 1];       sw += w01; }
        if (x0 >= 0 && x0 < WW && y0 + 1 >= 0 && y0 + 1 < HH)         { sx += w10 * im[(y0 + 1) * WW + x0];     sw += w10; }
        if (x0 + 1 >= 0 && x0 + 1 < WW && y0 + 1 >= 0 && y0 + 1 < HH) { sx += w11 * im[(y0 + 1) * WW + x0 + 1]; sw += w11; }
        sm[t] = s * sx + bv * sw;
    }
    __syncthreads();
    const float* kwr = kw + (size_t)(g * 64 + t) * 64;
    const float* vwr = vw + (size_t)(g * 64 + t) * 64;
    float ak = 0.f, av = 0.f;
#pragma unroll
    for (int c = 0; c < 64; c++) {
        float tv = sm[c];
        ak = fmaf(tv, kwr[c], ak);
        av = fmaf(tv, vwr[c], av);
    }
    kk[(size_t)bg * 4096 + j * 64 + t] = ak;
    vv[(size_t)bg * 4096 + j * 64 + t] = av;
}

// ---------------- K5b: pre-pack W2 into bf16 fragment order ----------------
__global__ void k_w2pack(const float* __restrict__ w2, unsigned short* __restrict__ w2p) {
    int idx = blockIdx.x * 256 + threadIdx.x;   // 16384
    int k = idx >> 7, n = idx & 127;
    int dest = ((((n >> 4) * 4 + (k >> 5)) * 64) + (((k >> 3) & 3) * 16) + (n & 15)) * 8 + (k & 7);
    w2p[dest] = (unsigned short)f2bf(w2[idx]);
}

// ---------------- K6: CPB bias MLP via bf16 MFMA (round-6 config: coef LDS, no occupancy forcing) ----------------
__global__ __launch_bounds__(256) void k_cpb(
    const float* __restrict__ vgrid, const unsigned short* __restrict__ w2p,
    const float* __restrict__ w1, const float* __restrict__ b1,
    const float* __restrict__ b2, const float* __restrict__ w3,
    const float* __restrict__ b3, float* __restrict__ bias) {
    __shared__ __align__(16) short w2fs[16384];
    __shared__ __align__(16) float coef[640];
    int tid = threadIdx.x;
    {
        const u32x4* src = (const u32x4*)w2p;
        u32x4* dst = (u32x4*)w2fs;
        for (int c = tid; c < 2048; c += 256) dst[c] = src[c];
    }
    if (tid < 256) coef[tid] = w1[tid];
    else if (tid < 384) coef[tid] = b1[tid - 256];
    else if (tid < 512) coef[tid] = b2[tid - 384];
    if (tid >= 128 && tid < 256) coef[512 + tid - 128] = w3[tid - 128];
    float bias3 = b3[0];
    __syncthreads();

    int lane = tid & 63;
    int wv = tid >> 6;
    int l15 = lane & 15;
    int quad = lane >> 4;

#pragma unroll 1
    for (int it = 0; it < 4; it++) {
        int p = (blockIdx.x * 4 + it) * 4 + wv;
        int bg = p >> 11;
        int i = (p >> 1) & 1023;
        int jbase = (p & 1) * 32;
        int hi = i >> 5, wi = i & 31;
        float qx = 2.0f * (float)wi / 31.0f - 1.0f;
        float qy = 2.0f * (float)hi / 31.0f - 1.0f;

        int jA = jbase + l15;
        float gkxA = vgrid[(bg * 64 + jA) * 2];
        float gkyA = vgrid[(bg * 64 + jA) * 2 + 1];
        float gkxB = vgrid[(bg * 64 + jA + 16) * 2];
        float gkyB = vgrid[(bg * 64 + jA + 16) * 2 + 1];
        float p0 = qx - gkxA, p1 = qy - gkyA;
        float s0a = copysignf(log1pf(fabsf(p0)), p0);
        float s1a = copysignf(log1pf(fabsf(p1)), p1);
        p0 = qx - gkxB; p1 = qy - gkyB;
        float s0b = copysignf(log1pf(fabsf(p0)), p0);
        float s1b = copysignf(log1pf(fabsf(p1)), p1);

        short8 hA[4], hB[4];
#pragma unroll
        for (int kc = 0; kc < 4; kc++) {
            f32x4 cu0 = *(const f32x4*)&coef[kc * 32 + quad * 8];
            f32x4 cu1 = *(const f32x4*)&coef[kc * 32 + quad * 8 + 4];
            f32x4 cv0 = *(const f32x4*)&coef[128 + kc * 32 + quad * 8];
            f32x4 cv1 = *(const f32x4*)&coef[128 + kc * 32 + quad * 8 + 4];
            f32x4 cb0 = *(const f32x4*)&coef[256 + kc * 32 + quad * 8];
            f32x4 cb1 = *(const f32x4*)&coef[256 + kc * 32 + quad * 8 + 4];
            u32x4 pa, pb;
#pragma unroll
            for (int j2 = 0; j2 < 4; j2++) {
                int e0 = 2 * j2, e1 = 2 * j2 + 1;
                float u0 = (e0 < 4) ? cu0[e0] : cu1[e0 - 4];
                float u1 = (e1 < 4) ? cu0[e1] : cu1[e1 - 4];
                float v0 = (e0 < 4) ? cv0[e0] : cv1[e0 - 4];
                float v1 = (e1 < 4) ? cv0[e1] : cv1[e1 - 4];
                float c0 = (e0 < 4) ? cb0[e0] : cb1[e0 - 4];
                float c1 = (e1 < 4) ? cb0[e1] : cb1[e1 - 4];
                unsigned a0 = __builtin_bit_cast(unsigned,
                    fmaxf(fmaf(s0a, u0, fmaf(s1a, v0, c0)), 0.f)) + 0x8000u;
                unsigned a1 = __builtin_bit_cast(unsigned,
                    fmaxf(fmaf(s0a, u1, fmaf(s1a, v1, c1)), 0.f)) + 0x8000u;
                pa[j2] = __builtin_amdgcn_perm(a1, a0, 0x07060302);
                unsigned b0 = __builtin_bit_cast(unsigned,
                    fmaxf(fmaf(s0b, u0, fmaf(s1b, v0, c0)), 0.f)) + 0x8000u;
                unsigned b1_ = __builtin_bit_cast(unsigned,
                    fmaxf(fmaf(s0b, u1, fmaf(s1b, v1, c1)), 0.f)) + 0x8000u;
                pb[j2] = __builtin_amdgcn_perm(b1_, b0, 0x07060302);
            }
            hA[kc] = __builtin_bit_cast(short8, pa);
            hB[kc] = __builtin_bit_cast(short8, pb);
        }

        float psumA = 0.f, psumB = 0.f;
#pragma unroll 1
        for (int nt = 0; nt < 8; nt++) {
            f32x4 accA = (f32x4){0.f, 0.f, 0.f, 0.f};
            f32x4 accB = (f32x4){0.f, 0.f, 0.f, 0.f};
#pragma unroll
            for (int kc = 0; kc < 4; kc++) {
                short8 af = *(const short8*)(w2fs + (((nt * 4 + kc) * 64) + lane) * 8);
                accA = __builtin_amdgcn_mfma_f32_16x16x32_bf16(af, hA[kc], accA, 0, 0, 0);
                accB = __builtin_amdgcn_mfma_f32_16x16x32_bf16(af, hB[kc], accB, 0, 0, 0);
            }
            f32x4 b2q = *(const f32x4*)&coef[384 + nt * 16 + quad * 4];
            f32x4 w3q = *(const f32x4*)&coef[512 + nt * 16 + quad * 4];
#pragma unroll
            for (int r = 0; r < 4; r++) {
                psumA = fmaf(fmaxf(accA[r] + b2q[r], 0.f), w3q[r], psumA);
                psumB = fmaf(fmaxf(accB[r] + b2q[r], 0.f), w3q[r], psumB);
            }
        }
        psumA += __shfl_xor(psumA, 16);
        psumA += __shfl_xor(psumA, 32);
        psumB += __shfl_xor(psumB, 16);
        psumB += __shfl_xor(psumB, 32);
        if (quad == 0) {
            bias[(size_t)(p * 2 + 0) * 16 + l15] = psumA + bias3;
            bias[(size_t)(p * 2 + 1) * 16 + l15] = psumB + bias3;
        }
    }
}

// ---------------- K7: attention via MFMA (flash-style, coalesced O store) ----------------
__global__ __launch_bounds__(256) void k_attn(
    const float* __restrict__ q, const float* __restrict__ kk,
    const float* __restrict__ vv, const float* __restrict__ bias,
    unsigned short* __restrict__ ao) {
    __shared__ __align__(16) short Ks[64][72];    // [j][d] bf16
    __shared__ __align__(16) short Vt[64][72];    // [d][j] bf16
    __shared__ __align__(16) short Qs[64][72];    // [i][d] bf16; reused as Ot[d][i]
    __shared__ __align__(16) short Ps[4][16][72]; // per-wave P
    int blk = blockIdx.x;
    int bg = blk >> 4;
    int chunk = blk & 15;
    int i0 = chunk * 64;
    int b = bg >> 3, g = bg & 7;
    int tid = threadIdx.x, lane = tid & 63, wv = tid >> 6;
    int l15 = lane & 15, quad = lane >> 4;

    const float* kbase = kk + (size_t)bg * 4096;
    const float* vbase = vv + (size_t)bg * 4096;
#pragma unroll
    for (int it = 0; it < 4; it++) {
        int e4 = it * 1024 + tid * 4;
        int j = e4 >> 6, d = e4 & 63;
        f32x4 k4 = *(const f32x4*)(kbase + e4);
        s16x4 s = {f2bf(k4.x), f2bf(k4.y), f2bf(k4.z), f2bf(k4.w)};
        *(s16x4*)&Ks[j][d] = s;
        f32x4 v4 = *(const f32x4*)(vbase + e4);
        Vt[d + 0][j] = f2bf(v4.x);
        Vt[d + 1][j] = f2bf(v4.y);
        Vt[d + 2][j] = f2bf(v4.z);
        Vt[d + 3][j] = f2bf(v4.w);
    }
    const float* qbase = q + (size_t)(b * CC + g * 64) * HWP + i0;
#pragma unroll
    for (int it = 0; it < 4; it++) {
        int e4 = it * 1024 + tid * 4;
        int d = e4 >> 6, i = e4 & 63;
        f32x4 q4 = *(const f32x4*)(qbase + (size_t)d * HWP + i);
        Qs[i + 0][d] = f2bf(q4.x * 0.125f);
        Qs[i + 1][d] = f2bf(q4.y * 0.125f);
        Qs[i + 2][d] = f2bf(q4.z * 0.125f);
        Qs[i + 3][d] = f2bf(q4.w * 0.125f);
    }
    __syncthreads();

    int iw = wv * 16;
    f32x4 Sacc[4];
#pragma unroll
    for (int nt = 0; nt < 4; nt++) Sacc[nt] = (f32x4){0.f, 0.f, 0.f, 0.f};
#pragma unroll
    for (int ks = 0; ks < 2; ks++) {
        short8 aq = *(const short8*)&Qs[iw + l15][quad * 8 + ks * 32];
#pragma unroll
        for (int nt = 0; nt < 4; nt++) {
            short8 bk = *(const short8*)&Ks[nt * 16 + l15][quad * 8 + ks * 32];
            Sacc[nt] = __builtin_amdgcn_mfma_f32_16x16x32_bf16(aq, bk, Sacc[nt], 0, 0, 0);
        }
    }
    const float* bp = bias + ((size_t)bg * 1024 + i0 + iw + quad * 4) * 64 + l15;
    float Sv[4][4];
#pragma unroll
    for (int nt = 0; nt < 4; nt++)
#pragma unroll
        for (int r = 0; r < 4; r++)
            Sv[nt][r] = Sacc[nt][r] + bp[r * 64 + nt * 16];
#pragma unroll
    for (int r = 0; r < 4; r++) {
        float m = fmaxf(fmaxf(Sv[0][r], Sv[1][r]), fmaxf(Sv[2][r], Sv[3][r]));
        m = fmaxf(m, __shfl_xor(m, 1));
        m = fmaxf(m, __shfl_xor(m, 2));
        m = fmaxf(m, __shfl_xor(m, 4));
        m = fmaxf(m, __shfl_xor(m, 8));
        float l = 0.f;
#pragma unroll
        for (int nt = 0; nt < 4; nt++) { Sv[nt][r] = expf(Sv[nt][r] - m); l += Sv[nt][r]; }
        l += __shfl_xor(l, 1);
        l += __shfl_xor(l, 2);
        l += __shfl_xor(l, 4);
        l += __shfl_xor(l, 8);
        float inv = 1.0f / l;
#pragma unroll
        for (int nt = 0; nt < 4; nt++)
            Ps[wv][quad * 4 + r][nt * 16 + l15] = f2bf(Sv[nt][r] * inv);
    }
    f32x4 Oacc[4];
#pragma unroll
    for (int nt = 0; nt < 4; nt++) Oacc[nt] = (f32x4){0.f, 0.f, 0.f, 0.f};
#pragma unroll
    for (int ks = 0; ks < 2; ks++) {
        short8 ap = *(const short8*)&Ps[wv][l15][quad * 8 + ks * 32];
#pragma unroll
        for (int nt = 0; nt < 4; nt++) {
            short8 bv = *(const short8*)&Vt[nt * 16 + l15][quad * 8 + ks * 32];
            Oacc[nt] = __builtin_amdgcn_mfma_f32_16x16x32_bf16(ap, bv, Oacc[nt], 0, 0, 0);
        }
    }
    __syncthreads();   // all waves done reading Qs
#pragma unroll
    for (int nt = 0; nt < 4; nt++) {
        s16x4 o4 = {f2bf(Oacc[nt][0]), f2bf(Oacc[nt][1]), f2bf(Oacc[nt][2]), f2bf(Oacc[nt][3])};
        *(s16x4*)&Qs[nt * 16 + l15][iw + quad * 4] = o4;
    }
    __syncthreads();
    {
        int d = tid >> 2;
        int ic = (tid & 3) * 16;
        short8 a = *(const short8*)&Qs[d][ic];
        short8 c = *(const short8*)&Qs[d][ic + 8];
        unsigned short* dst = ao + (size_t)(b * CC + g * 64 + d) * HWP + i0 + ic;
        *(short8*)dst = a;
        *(short8*)(dst + 8) = c;
    }
}

// ---------------- K8/K10/K11: tiled bf16-MFMA GEMM (A prepacked bf16) ----------------
template<int EPI, int KD, int MT, bool BBF, bool BN>
__global__ __launch_bounds__(256) void k_gemm(
    const unsigned short* __restrict__ A, const void* __restrict__ Bp,
    const float* __restrict__ resid, const float* __restrict__ bias,
    void* __restrict__ outp,
    const float* __restrict__ bns, const float* __restrict__ bnb) {
    constexpr int MM = MT * 64;
    __shared__ __align__(16) short As[64][72];
    __shared__ __align__(16) short Bs[64][72];
    int tid = threadIdx.x;
    int blk = blockIdx.x;
    int mt = blk & (MT - 1);
    int nb = blk / MT;              // 0..31
    int bb = nb >> 4, nt = nb & 15;
    int m0 = mt * 64, i0 = nt * 64;
    int lane = tid & 63, wv = tid >> 6;
    int wm = (wv >> 1) * 32, wn = (wv & 1) * 32;
    int l15 = lane & 15, quad = lane >> 4;
    const unsigned short* Af = A + (size_t)m0 * KD;
    const float* Bf = (const float*)Bp;
    const unsigned short* Bh = (const unsigned short*)Bp;
    const float invs = 1.0f / sqrtf(1.0f + EPS);

    f32x4 acc[2][2];
#pragma unroll
    for (int a = 0; a < 2; a++)
#pragma unroll
        for (int c = 0; c < 2; c++) acc[a][c] = (f32x4){0.f, 0.f, 0.f, 0.f};

    for (int k0 = 0; k0 < KD; k0 += 64) {
        __syncthreads();
        {
            int kk4 = (tid & 15) * 4;
            int myb = tid >> 4;
#pragma unroll
            for (int p = 0; p < 4; p++) {
                int my = myb + p * 16;
                u16x4 v = *(const u16x4*)(Af + (size_t)my * KD + k0 + kk4);
                *(u16x4*)&As[my][kk4] = v;
            }
        }
        {
            int i4 = (tid & 15) * 4;
            int kyb = tid >> 4;
#pragma unroll
            for (int p = 0; p < 4; p++) {
                int ky = kyb + p * 16;
                size_t goff = (size_t)bb * KD * HWP + (size_t)(k0 + ky) * HWP + i0 + i4;
                if (BBF) {
                    u16x4 v = *(const u16x4*)(Bh + goff);
                    Bs[i4 + 0][ky] = (short)v.x;
                    Bs[i4 + 1][ky] = (short)v.y;
                    Bs[i4 + 2][ky] = (short)v.z;
                    Bs[i4 + 3][ky] = (short)v.w;
                } else {
                    f32x4 v = *(const f32x4*)(Bf + goff);
                    if (BN) {
                        float sc = bns[k0 + ky] * invs;
                        float sh = bnb[k0 + ky];
                        v.x = fmaf(v.x, sc, sh);
                        v.y = fmaf(v.y, sc, sh);
                        v.z = fmaf(v.z, sc, sh);
                        v.w = fmaf(v.w, sc, sh);
                    }
                    Bs[i4 + 0][ky] = f2bf(v.x);
                    Bs[i4 + 1][ky] = f2bf(v.y);
                    Bs[i4 + 2][ky] = f2bf(v.z);
                    Bs[i4 + 3][ky] = f2bf(v.w);
                }
            }
        }
        __syncthreads();
#pragma unroll
        for (int ks = 0; ks < 2; ks++) {
            short8 af0 = *(const short8*)&As[wm + l15][ks * 32 + quad * 8];
            short8 af1 = *(const short8*)&As[wm + 16 + l15][ks * 32 + quad * 8];
            short8 bf0 = *(const short8*)&Bs[wn + l15][ks * 32 + quad * 8];
            short8 bf1 = *(const short8*)&Bs[wn + 16 + l15][ks * 32 + quad * 8];
            acc[0][0] = __builtin_amdgcn_mfma_f32_16x16x32_bf16(af0, bf0, acc[0][0], 0, 0, 0);
            acc[0][1] = __builtin_amdgcn_mfma_f32_16x16x32_bf16(af0, bf1, acc[0][1], 0, 0, 0);
            acc[1][0] = __builtin_amdgcn_mfma_f32_16x16x32_bf16(af1, bf0, acc[1][0], 0, 0, 0);
            acc[1][1] = __builtin_amdgcn_mfma_f32_16x16x32_bf16(af1, bf1, acc[1][1], 0, 0, 0);
        }
    }

    float* outF = (float*)outp;
    unsigned short* outH = (unsigned short*)outp;
#pragma unroll
    for (int im = 0; im < 2; im++) {
#pragma unroll
        for (int r = 0; r < 4; r++) {
            int m = m0 + wm + im * 16 + quad * 4 + r;
            float bv = bias[m];
#pragma unroll
            for (int in_ = 0; in_ < 2; in_++) {
                int n = i0 + wn + in_ * 16 + l15;
                size_t idx = ((size_t)bb * MM + m) * HWP + n;
                float v = acc[im][in_][r] + bv;
                if constexpr (EPI == 1) {
                    float ge = 0.5f * v * (1.0f + erff(v * 0.7071067811865475f));
                    outH[idx] = (unsigned short)f2bf(ge);
                } else {
                    outF[idx] = v + resid[idx];
                }
            }
        }
    }
}

extern "C" void kernel_launch(void* const* d_in, const int* in_sizes, int n_in,
                              void* d_out, int out_size, void* d_ws, size_t ws_size,
                              hipStream_t stream) {
    const float* x      = (const float*)d_in[0];
    const float* bn1_g  = (const float*)d_in[1];
    const float* bn1_b  = (const float*)d_in[2];
    const float* bn2_g  = (const float*)d_in[3];
    const float* bn2_b  = (const float*)d_in[4];
    const float* qw     = (const float*)d_in[5];
    const float* kw     = (const float*)d_in[6];
    const float* vw     = (const float*)d_in[7];
    const float* out_w  = (const float*)d_in[8];
    const float* out_b  = (const float*)d_in[9];
    const float* off_dw_w = (const float*)d_in[10];
    const float* off_dw_b = (const float*)d_in[11];
    const float* off_pw_w = (const float*)d_in[12];
    const float* cpb_w1 = (const float*)d_in[13];
    const float* cpb_b1 = (const float*)d_in[14];
    const float* cpb_w2 = (const float*)d_in[15];
    const float* cpb_b2 = (const float*)d_in[16];
    const float* cpb_w3 = (const float*)d_in[17];
    const float* cpb_b3 = (const float*)d_in[18];
    const float* mlp_w1 = (const float*)d_in[19];
    const float* mlp_b1 = (const float*)d_in[20];
    const float* mlp_w2 = (const float*)d_in[21];
    const float* mlp_b2 = (const float*)d_in[22];

    float* ws = (float*)d_ws;
    float* q     = ws + 1048576;      // 1,048,576
    float* vgrid = ws + 2097152;      // 2,048
    float* kk    = ws + 2164736;      // 65,536
    float* vv    = ws + 2230272;      // 65,536
    unsigned short* w2p = (unsigned short*)(ws + 2295808);  // 16,384 bf16
    unsigned short* ao  = (unsigned short*)(ws + 2312192);  // 1,048,576 bf16
    float* xo    = ws + 3360768;      // 1,048,576
    float* h1of  = ws + 4409344;      // bias (1M floats), then h1o bf16 (4M ushorts)
    float* biasb = h1of;
    unsigned short* h1o = (unsigned short*)h1of;
    // prepacked bf16 weights: qw(32768) | out_w(262144) | mlp_w1(1048576) | mlp_w2(1048576)
    unsigned short* wp  = (unsigned short*)(ws + 6506496);  // 2,392,064 ushorts
    unsigned short* qwp  = wp;
    unsigned short* owp  = wp + 32768;
    unsigned short* w1p  = wp + 294912;
    unsigned short* w2mp = wp + 1343488;

    hipLaunchKernelGGL(k_wpack, dim3(9344), dim3(256), 0, stream, qw, out_w, mlp_w1, mlp_w2, wp);
    hipLaunchKernelGGL(k_qgemm, dim3(256), dim3(256), 0, stream, x, bn1_g, bn1_b, qwp, q);
    hipLaunchKernelGGL(k_off, dim3(1024), dim3(64), 0, stream, q, off_dw_w, off_dw_b, off_pw_w, vgrid);
    hipLaunchKernelGGL(k_skv, dim3(1024), dim3(64), 0, stream, x, bn1_g, bn1_b, vgrid, kw, vw, kk, vv);
    hipLaunchKernelGGL(k_w2pack, dim3(64), dim3(256), 0, stream, cpb_w2, w2p);
    hipLaunchKernelGGL(k_cpb, dim3(2048), dim3(256), 0, stream,
                       vgrid, w2p, cpb_w1, cpb_b1, cpb_b2, cpb_w3, cpb_b3, biasb);
    hipLaunchKernelGGL(k_attn, dim3(256), dim3(256), 0, stream, q, kk, vv, biasb, ao);
    k_gemm<0, 512, 8, true, false><<<dim3(256), dim3(256), 0, stream>>>(
        owp, ao, x, out_b, xo, nullptr, nullptr);
    k_gemm<1, 512, 32, false, true><<<dim3(1024), dim3(256), 0, stream>>>(
        w1p, xo, nullptr, mlp_b1, h1o, bn2_g, bn2_b);
    k_gemm<2, 2048, 8, true, false><<<dim3(256), dim3(256), 0, stream>>>(
        w2mp, h1o, xo, mlp_b2, d_out, nullptr, nullptr);
}

// Round 9
// 276.059 us; speedup vs baseline: 1.2469x; 1.0308x over previous
//
#include <hip/hip_runtime.h>
#include <hip/hip_bf16.h>
#include <math.h>

// Problem constants
#define BB 2
#define CC 512
#define HH 32
#define WW 32
#define HWP 1024      // H*W
#define GG 8
#define DH 64
#define HD 8
#define WD 8
#define JJ 64         // HD*WD
#define BG 16         // BB*GG
#define EPS 1e-5f

typedef __attribute__((ext_vector_type(8))) short short8;
typedef __attribute__((ext_vector_type(4))) short s16x4;
typedef __attribute__((ext_vector_type(4))) float f32x4;
typedef __attribute__((ext_vector_type(4))) unsigned short u16x4;
typedef __attribute__((ext_vector_type(4))) unsigned int u32x4;

// RNE float -> bf16 bits
static __device__ __forceinline__ short f2bf(float x) {
    unsigned u = __builtin_bit_cast(unsigned, x);
    u += 0x7FFFu + ((u >> 16) & 1u);
    return (short)(u >> 16);
}

// ---------------- K0: pre-pack ALL weights to bf16 ----------------
// wp: qw(32768) | out_w(262144) | mlp_w1(1048576) | mlp_w2(1048576); then cpb_w2 frag-order into w2p.
__global__ void k_wpack(const float* __restrict__ qw, const float* __restrict__ ow,
                        const float* __restrict__ w1, const float* __restrict__ w2,
                        const float* __restrict__ cw2, unsigned short* __restrict__ wp,
                        unsigned short* __restrict__ w2p) {
    int idx = blockIdx.x * 256 + threadIdx.x;
    if (idx < 2392064) {
        float v;
        if (idx < 32768) v = qw[idx];
        else if (idx < 294912) v = ow[idx - 32768];
        else if (idx < 1343488) v = w1[idx - 294912];
        else v = w2[idx - 1343488];
        wp[idx] = (unsigned short)f2bf(v);
    } else if (idx < 2408448) {
        int i2 = idx - 2392064;
        int k = i2 >> 7, n = i2 & 127;
        int dest = ((((n >> 4) * 4 + (k >> 5)) * 64) + (((k >> 3) & 3) * 16) + (n & 15)) * 8 + (k & 7);
        w2p[dest] = (unsigned short)f2bf(cw2[i2]);
    }
}

// ---------------- K2: q grouped 1x1 conv via MFMA (BN1 folded in B-staging) ----------------
__global__ __launch_bounds__(256) void k_qgemm(
    const float* __restrict__ x, const float* __restrict__ g1,
    const float* __restrict__ b1, const unsigned short* __restrict__ qwp,
    float* __restrict__ q) {
    __shared__ __align__(16) short As[64][72];
    __shared__ __align__(16) short Bs[64][72];
    int blk = blockIdx.x;
    int bg = blk >> 4, nt = blk & 15;
    int b = bg >> 3, g = bg & 7;
    int i0 = nt * 64;
    int tid = threadIdx.x, lane = tid & 63, wv = tid >> 6;
    int wm = (wv >> 1) * 32, wn = (wv & 1) * 32;
    int l15 = lane & 15, quad = lane >> 4;
    const float invs = 1.0f / sqrtf(1.0f + EPS);
    {
        int c4 = (tid & 15) * 4;
        int ob = tid >> 4;
#pragma unroll
        for (int p = 0; p < 4; p++) {
            int o = ob + p * 16;
            u16x4 v = *(const u16x4*)(qwp + (size_t)(g * 64 + o) * 64 + c4);
            *(u16x4*)&As[o][c4] = v;
        }
    }
    {
        int i4 = (tid & 15) * 4;
        int cb = tid >> 4;
#pragma unroll
        for (int p = 0; p < 4; p++) {
            int c = cb + p * 16;
            f32x4 v = *(const f32x4*)(x + (size_t)(b * CC + g * 64 + c) * HWP + i0 + i4);
            float sc = g1[g * 64 + c] * invs;
            float sh = b1[g * 64 + c];
            Bs[i4 + 0][c] = f2bf(fmaf(v.x, sc, sh));
            Bs[i4 + 1][c] = f2bf(fmaf(v.y, sc, sh));
            Bs[i4 + 2][c] = f2bf(fmaf(v.z, sc, sh));
            Bs[i4 + 3][c] = f2bf(fmaf(v.w, sc, sh));
        }
    }
    __syncthreads();
    f32x4 acc[2][2];
#pragma unroll
    for (int a = 0; a < 2; a++)
#pragma unroll
        for (int c = 0; c < 2; c++) acc[a][c] = (f32x4){0.f, 0.f, 0.f, 0.f};
#pragma unroll
    for (int ks = 0; ks < 2; ks++) {
        short8 af0 = *(const short8*)&As[wm + l15][ks * 32 + quad * 8];
        short8 af1 = *(const short8*)&As[wm + 16 + l15][ks * 32 + quad * 8];
        short8 bf0 = *(const short8*)&Bs[wn + l15][ks * 32 + quad * 8];
        short8 bf1 = *(const short8*)&Bs[wn + 16 + l15][ks * 32 + quad * 8];
        acc[0][0] = __builtin_amdgcn_mfma_f32_16x16x32_bf16(af0, bf0, acc[0][0], 0, 0, 0);
        acc[0][1] = __builtin_amdgcn_mfma_f32_16x16x32_bf16(af0, bf1, acc[0][1], 0, 0, 0);
        acc[1][0] = __builtin_amdgcn_mfma_f32_16x16x32_bf16(af1, bf0, acc[1][0], 0, 0, 0);
        acc[1][1] = __builtin_amdgcn_mfma_f32_16x16x32_bf16(af1, bf1, acc[1][1], 0, 0, 0);
    }
#pragma unroll
    for (int im = 0; im < 2; im++)
#pragma unroll
        for (int r = 0; r < 4; r++) {
            int m = wm + im * 16 + quad * 4 + r;
#pragma unroll
            for (int in_ = 0; in_ < 2; in_++) {
                int n = wn + in_ * 16 + l15;
                q[(size_t)(bg * 64 + m) * HWP + i0 + n] = acc[im][in_][r];
            }
        }
}

// ---------------- K3: offsets -> vgrid ----------------
__global__ void k_off(const float* __restrict__ q, const float* __restrict__ dww,
                      const float* __restrict__ dwb, const float* __restrict__ pw,
                      float* __restrict__ vgrid) {
    int blk = blockIdx.x;          // bg*64 + hd*8 + wd
    int bg = blk >> 6;
    int hd = (blk >> 3) & 7;
    int wd = blk & 7;
    int ch = threadIdx.x;
    const float* qch = q + (size_t)(bg * 64 + ch) * HWP;
    float acc = 0.f;
#pragma unroll
    for (int kh = 0; kh < 6; kh++) {
        int hin = hd * 4 - 1 + kh;
        if (hin < 0 || hin >= HH) continue;
#pragma unroll
        for (int kw_ = 0; kw_ < 6; kw_++) {
            int win = wd * 4 - 1 + kw_;
            if (win < 0 || win >= WW) continue;
            acc = fmaf(qch[hin * WW + win], dww[ch * 36 + kh * 6 + kw_], acc);
        }
    }
    acc += dwb[ch];
    float ge = 0.5f * acc * (1.0f + erff(acc * 0.7071067811865475f));
    float p0 = ge * pw[ch];
    float p1 = ge * pw[64 + ch];
#pragma unroll
    for (int off = 32; off; off >>= 1) {
        p0 += __shfl_xor(p0, off);
        p1 += __shfl_xor(p1, off);
    }
    if (ch == 0) {
        float off0 = tanhf(p0) * 4.0f;
        float off1 = tanhf(p1) * 4.0f;
        float vx = (float)wd + off0;
        float vy = (float)hd + off1;
        float nx = 2.0f * vx / 7.0f - 1.0f;
        float ny = 2.0f * vy / 7.0f - 1.0f;
        vgrid[blk * 2] = nx;
        vgrid[blk * 2 + 1] = ny;
    }
}

// ---------------- K4+K5 fused: grid_sample (BN1 folded) + k/v grouped conv ----------------
__global__ __launch_bounds__(64) void k_skv(
    const float* __restrict__ x, const float* __restrict__ g1,
    const float* __restrict__ b1, const float* __restrict__ vgrid,
    const float* __restrict__ kw, const float* __restrict__ vw,
    float* __restrict__ kk, float* __restrict__ vv) {
    __shared__ float sm[64];
    int blk = blockIdx.x;          // bg*64 + j
    int bg = blk >> 6, j = blk & 63;
    int g = bg & 7, b = bg >> 3;
    int t = threadIdx.x;
    const float invs = 1.0f / sqrtf(1.0f + EPS);
    {
        int cg = g * 64 + t;
        float s = g1[cg] * invs;
        float bv = b1[cg];
        float nx = vgrid[blk * 2];
        float ny = vgrid[blk * 2 + 1];
        float gx = (nx + 1.0f) * 16.0f - 0.5f;
        float gy = (ny + 1.0f) * 16.0f - 0.5f;
        float x0f = floorf(gx), y0f = floorf(gy);
        float wx = gx - x0f, wy = gy - y0f;
        int x0 = (int)x0f, y0 = (int)y0f;
        const float* im = x + (size_t)(b * CC + cg) * HWP;
        float sx = 0.f, sw = 0.f;
        float w00 = (1 - wx) * (1 - wy), w01 = wx * (1 - wy);
        float w10 = (1 - wx) * wy, w11 = wx * wy;
        if (x0 >= 0 && x0 < WW && y0 >= 0 && y0 < HH)                 { sx += w00 * im[y0 * WW + x0];           sw += w00; }
        if (x0 + 1 >= 0 && x0 + 1 < WW && y0 >= 0 && y0 < HH)         { sx += w01 * im[y0 * WW + x0 + 1];       sw += w01; }
        if (x0 >= 0 && x0 < WW && y0 + 1 >= 0 && y0 + 1 < HH)         { sx += w10 * im[(y0 + 1) * WW + x0];     sw += w10; }
        if (x0 + 1 >= 0 && x0 + 1 < WW && y0 + 1 >= 0 && y0 + 1 < HH) { sx += w11 * im[(y0 + 1) * WW + x0 + 1]; sw += w11; }
        sm[t] = s * sx + bv * sw;
    }
    __syncthreads();
    const float* kwr = kw + (size_t)(g * 64 + t) * 64;
    const float* vwr = vw + (size_t)(g * 64 + t) * 64;
    float ak = 0.f, av = 0.f;
#pragma unroll
    for (int c = 0; c < 64; c++) {
        float tv = sm[c];
        ak = fmaf(tv, kwr[c], ak);
        av = fmaf(tv, vwr[c], av);
    }
    kk[(size_t)bg * 4096 + j * 64 + t] = ak;
    vv[(size_t)bg * 4096 + j * 64 + t] = av;
}

// ---------------- K6: CPB bias MLP via bf16 MFMA (v5: nt unroll 2 for ILP) ----------------
__global__ __launch_bounds__(256) void k_cpb(
    const float* __restrict__ vgrid, const unsigned short* __restrict__ w2p,
    const float* __restrict__ w1, const float* __restrict__ b1,
    const float* __restrict__ b2, const float* __restrict__ w3,
    const float* __restrict__ b3, float* __restrict__ bias) {
    __shared__ __align__(16) short w2fs[16384];
    __shared__ __align__(16) float coef[640];
    int tid = threadIdx.x;
    {
        const u32x4* src = (const u32x4*)w2p;
        u32x4* dst = (u32x4*)w2fs;
        for (int c = tid; c < 2048; c += 256) dst[c] = src[c];
    }
    if (tid < 256) coef[tid] = w1[tid];
    else if (tid < 384) coef[tid] = b1[tid - 256];
    else if (tid < 512) coef[tid] = b2[tid - 384];
    if (tid >= 128 && tid < 256) coef[512 + tid - 128] = w3[tid - 128];
    float bias3 = b3[0];
    __syncthreads();

    int lane = tid & 63;
    int wv = tid >> 6;
    int l15 = lane & 15;
    int quad = lane >> 4;

#pragma unroll 1
    for (int it = 0; it < 4; it++) {
        int p = (blockIdx.x * 4 + it) * 4 + wv;
        int bg = p >> 11;
        int i = (p >> 1) & 1023;
        int jbase = (p & 1) * 32;
        int hi = i >> 5, wi = i & 31;
        float qx = 2.0f * (float)wi / 31.0f - 1.0f;
        float qy = 2.0f * (float)hi / 31.0f - 1.0f;

        int jA = jbase + l15;
        float gkxA = vgrid[(bg * 64 + jA) * 2];
        float gkyA = vgrid[(bg * 64 + jA) * 2 + 1];
        float gkxB = vgrid[(bg * 64 + jA + 16) * 2];
        float gkyB = vgrid[(bg * 64 + jA + 16) * 2 + 1];
        float p0 = qx - gkxA, p1 = qy - gkyA;
        float s0a = copysignf(log1pf(fabsf(p0)), p0);
        float s1a = copysignf(log1pf(fabsf(p1)), p1);
        p0 = qx - gkxB; p1 = qy - gkyB;
        float s0b = copysignf(log1pf(fabsf(p0)), p0);
        float s1b = copysignf(log1pf(fabsf(p1)), p1);

        short8 hA[4], hB[4];
#pragma unroll
        for (int kc = 0; kc < 4; kc++) {
            f32x4 cu0 = *(const f32x4*)&coef[kc * 32 + quad * 8];
            f32x4 cu1 = *(const f32x4*)&coef[kc * 32 + quad * 8 + 4];
            f32x4 cv0 = *(const f32x4*)&coef[128 + kc * 32 + quad * 8];
            f32x4 cv1 = *(const f32x4*)&coef[128 + kc * 32 + quad * 8 + 4];
            f32x4 cb0 = *(const f32x4*)&coef[256 + kc * 32 + quad * 8];
            f32x4 cb1 = *(const f32x4*)&coef[256 + kc * 32 + quad * 8 + 4];
            u32x4 pa, pb;
#pragma unroll
            for (int j2 = 0; j2 < 4; j2++) {
                int e0 = 2 * j2, e1 = 2 * j2 + 1;
                float u0 = (e0 < 4) ? cu0[e0] : cu1[e0 - 4];
                float u1 = (e1 < 4) ? cu0[e1] : cu1[e1 - 4];
                float v0 = (e0 < 4) ? cv0[e0] : cv1[e0 - 4];
                float v1 = (e1 < 4) ? cv0[e1] : cv1[e1 - 4];
                float c0 = (e0 < 4) ? cb0[e0] : cb1[e0 - 4];
                float c1 = (e1 < 4) ? cb0[e1] : cb1[e1 - 4];
                unsigned a0 = __builtin_bit_cast(unsigned,
                    fmaxf(fmaf(s0a, u0, fmaf(s1a, v0, c0)), 0.f)) + 0x8000u;
                unsigned a1 = __builtin_bit_cast(unsigned,
                    fmaxf(fmaf(s0a, u1, fmaf(s1a, v1, c1)), 0.f)) + 0x8000u;
                pa[j2] = __builtin_amdgcn_perm(a1, a0, 0x07060302);
                unsigned b0 = __builtin_bit_cast(unsigned,
                    fmaxf(fmaf(s0b, u0, fmaf(s1b, v0, c0)), 0.f)) + 0x8000u;
                unsigned b1_ = __builtin_bit_cast(unsigned,
                    fmaxf(fmaf(s0b, u1, fmaf(s1b, v1, c1)), 0.f)) + 0x8000u;
                pb[j2] = __builtin_amdgcn_perm(b1_, b0, 0x07060302);
            }
            hA[kc] = __builtin_bit_cast(short8, pa);
            hB[kc] = __builtin_bit_cast(short8, pb);
        }

        float psumA = 0.f, psumB = 0.f;
        // unroll 2: two independent MFMA chains in flight (ILP), without the
        // full-unroll VGPR hoist of all 32 fragments (r4 lesson).
#pragma unroll 2
        for (int nt = 0; nt < 8; nt++) {
            f32x4 accA = (f32x4){0.f, 0.f, 0.f, 0.f};
            f32x4 accB = (f32x4){0.f, 0.f, 0.f, 0.f};
#pragma unroll
            for (int kc = 0; kc < 4; kc++) {
                short8 af = *(const short8*)(w2fs + (((nt * 4 + kc) * 64) + lane) * 8);
                accA = __builtin_amdgcn_mfma_f32_16x16x32_bf16(af, hA[kc], accA, 0, 0, 0);
                accB = __builtin_amdgcn_mfma_f32_16x16x32_bf16(af, hB[kc], accB, 0, 0, 0);
            }
            f32x4 b2q = *(const f32x4*)&coef[384 + nt * 16 + quad * 4];
            f32x4 w3q = *(const f32x4*)&coef[512 + nt * 16 + quad * 4];
#pragma unroll
            for (int r = 0; r < 4; r++) {
                psumA = fmaf(fmaxf(accA[r] + b2q[r], 0.f), w3q[r], psumA);
                psumB = fmaf(fmaxf(accB[r] + b2q[r], 0.f), w3q[r], psumB);
            }
        }
        psumA += __shfl_xor(psumA, 16);
        psumA += __shfl_xor(psumA, 32);
        psumB += __shfl_xor(psumB, 16);
        psumB += __shfl_xor(psumB, 32);
        if (quad == 0) {
            bias[(size_t)(p * 2 + 0) * 16 + l15] = psumA + bias3;
            bias[(size_t)(p * 2 + 1) * 16 + l15] = psumB + bias3;
        }
    }
}

// ---------------- K7: attention via MFMA (flash-style, coalesced O store) ----------------
__global__ __launch_bounds__(256) void k_attn(
    const float* __restrict__ q, const float* __restrict__ kk,
    const float* __restrict__ vv, const float* __restrict__ bias,
    unsigned short* __restrict__ ao) {
    __shared__ __align__(16) short Ks[64][72];
    __shared__ __align__(16) short Vt[64][72];
    __shared__ __align__(16) short Qs[64][72];
    __shared__ __align__(16) short Ps[4][16][72];
    int blk = blockIdx.x;
    int bg = blk >> 4;
    int chunk = blk & 15;
    int i0 = chunk * 64;
    int b = bg >> 3, g = bg & 7;
    int tid = threadIdx.x, lane = tid & 63, wv = tid >> 6;
    int l15 = lane & 15, quad = lane >> 4;

    const float* kbase = kk + (size_t)bg * 4096;
    const float* vbase = vv + (size_t)bg * 4096;
#pragma unroll
    for (int it = 0; it < 4; it++) {
        int e4 = it * 1024 + tid * 4;
        int j = e4 >> 6, d = e4 & 63;
        f32x4 k4 = *(const f32x4*)(kbase + e4);
        s16x4 s = {f2bf(k4.x), f2bf(k4.y), f2bf(k4.z), f2bf(k4.w)};
        *(s16x4*)&Ks[j][d] = s;
        f32x4 v4 = *(const f32x4*)(vbase + e4);
        Vt[d + 0][j] = f2bf(v4.x);
        Vt[d + 1][j] = f2bf(v4.y);
        Vt[d + 2][j] = f2bf(v4.z);
        Vt[d + 3][j] = f2bf(v4.w);
    }
    const float* qbase = q + (size_t)(b * CC + g * 64) * HWP + i0;
#pragma unroll
    for (int it = 0; it < 4; it++) {
        int e4 = it * 1024 + tid * 4;
        int d = e4 >> 6, i = e4 & 63;
        f32x4 q4 = *(const f32x4*)(qbase + (size_t)d * HWP + i);
        Qs[i + 0][d] = f2bf(q4.x * 0.125f);
        Qs[i + 1][d] = f2bf(q4.y * 0.125f);
        Qs[i + 2][d] = f2bf(q4.z * 0.125f);
        Qs[i + 3][d] = f2bf(q4.w * 0.125f);
    }
    __syncthreads();

    int iw = wv * 16;
    f32x4 Sacc[4];
#pragma unroll
    for (int nt = 0; nt < 4; nt++) Sacc[nt] = (f32x4){0.f, 0.f, 0.f, 0.f};
#pragma unroll
    for (int ks = 0; ks < 2; ks++) {
        short8 aq = *(const short8*)&Qs[iw + l15][quad * 8 + ks * 32];
#pragma unroll
        for (int nt = 0; nt < 4; nt++) {
            short8 bk = *(const short8*)&Ks[nt * 16 + l15][quad * 8 + ks * 32];
            Sacc[nt] = __builtin_amdgcn_mfma_f32_16x16x32_bf16(aq, bk, Sacc[nt], 0, 0, 0);
        }
    }
    const float* bp = bias + ((size_t)bg * 1024 + i0 + iw + quad * 4) * 64 + l15;
    float Sv[4][4];
#pragma unroll
    for (int nt = 0; nt < 4; nt++)
#pragma unroll
        for (int r = 0; r < 4; r++)
            Sv[nt][r] = Sacc[nt][r] + bp[r * 64 + nt * 16];
#pragma unroll
    for (int r = 0; r < 4; r++) {
        float m = fmaxf(fmaxf(Sv[0][r], Sv[1][r]), fmaxf(Sv[2][r], Sv[3][r]));
        m = fmaxf(m, __shfl_xor(m, 1));
        m = fmaxf(m, __shfl_xor(m, 2));
        m = fmaxf(m, __shfl_xor(m, 4));
        m = fmaxf(m, __shfl_xor(m, 8));
        float l = 0.f;
#pragma unroll
        for (int nt = 0; nt < 4; nt++) { Sv[nt][r] = expf(Sv[nt][r] - m); l += Sv[nt][r]; }
        l += __shfl_xor(l, 1);
        l += __shfl_xor(l, 2);
        l += __shfl_xor(l, 4);
        l += __shfl_xor(l, 8);
        float inv = 1.0f / l;
#pragma unroll
        for (int nt = 0; nt < 4; nt++)
            Ps[wv][quad * 4 + r][nt * 16 + l15] = f2bf(Sv[nt][r] * inv);
    }
    f32x4 Oacc[4];
#pragma unroll
    for (int nt = 0; nt < 4; nt++) Oacc[nt] = (f32x4){0.f, 0.f, 0.f, 0.f};
#pragma unroll
    for (int ks = 0; ks < 2; ks++) {
        short8 ap = *(const short8*)&Ps[wv][l15][quad * 8 + ks * 32];
#pragma unroll
        for (int nt = 0; nt < 4; nt++) {
            short8 bv = *(const short8*)&Vt[nt * 16 + l15][quad * 8 + ks * 32];
            Oacc[nt] = __builtin_amdgcn_mfma_f32_16x16x32_bf16(ap, bv, Oacc[nt], 0, 0, 0);
        }
    }
    __syncthreads();
#pragma unroll
    for (int nt = 0; nt < 4; nt++) {
        s16x4 o4 = {f2bf(Oacc[nt][0]), f2bf(Oacc[nt][1]), f2bf(Oacc[nt][2]), f2bf(Oacc[nt][3])};
        *(s16x4*)&Qs[nt * 16 + l15][iw + quad * 4] = o4;
    }
    __syncthreads();
    {
        int d = tid >> 2;
        int ic = (tid & 3) * 16;
        short8 a = *(const short8*)&Qs[d][ic];
        short8 c = *(const short8*)&Qs[d][ic + 8];
        unsigned short* dst = ao + (size_t)(b * CC + g * 64 + d) * HWP + i0 + ic;
        *(short8*)dst = a;
        *(short8*)(dst + 8) = c;
    }
}

// ---------------- K8/K10/K11: tiled bf16-MFMA GEMM (A prepacked bf16) ----------------
// EPI 0: +resid fp32.  EPI 1: gelu bf16.  EPI 2: +resid fp32.
// EPI 3: +resid fp32 AND bf16(BN2(.)) to out2 (outproj fused epilogue).
template<int EPI, int KD, int MT, bool BBF>
__global__ __launch_bounds__(256) void k_gemm(
    const unsigned short* __restrict__ A, const void* __restrict__ Bp,
    const float* __restrict__ resid, const float* __restrict__ bias,
    void* __restrict__ outp, unsigned short* __restrict__ out2,
    const float* __restrict__ bns, const float* __restrict__ bnb) {
    constexpr int MM = MT * 64;
    __shared__ __align__(16) short As[64][72];
    __shared__ __align__(16) short Bs[64][72];
    int tid = threadIdx.x;
    int blk = blockIdx.x;
    int mt = blk & (MT - 1);
    int nb = blk / MT;              // 0..31
    int bb = nb >> 4, nt = nb & 15;
    int m0 = mt * 64, i0 = nt * 64;
    int lane = tid & 63, wv = tid >> 6;
    int wm = (wv >> 1) * 32, wn = (wv & 1) * 32;
    int l15 = lane & 15, quad = lane >> 4;
    const unsigned short* Af = A + (size_t)m0 * KD;
    const float* Bf = (const float*)Bp;
    const unsigned short* Bh = (const unsigned short*)Bp;
    const float invs = 1.0f / sqrtf(1.0f + EPS);

    f32x4 acc[2][2];
#pragma unroll
    for (int a = 0; a < 2; a++)
#pragma unroll
        for (int c = 0; c < 2; c++) acc[a][c] = (f32x4){0.f, 0.f, 0.f, 0.f};

    for (int k0 = 0; k0 < KD; k0 += 64) {
        __syncthreads();
        {
            int kk4 = (tid & 15) * 4;
            int myb = tid >> 4;
#pragma unroll
            for (int p = 0; p < 4; p++) {
                int my = myb + p * 16;
                u16x4 v = *(const u16x4*)(Af + (size_t)my * KD + k0 + kk4);
                *(u16x4*)&As[my][kk4] = v;
            }
        }
        {
            int i4 = (tid & 15) * 4;
            int kyb = tid >> 4;
#pragma unroll
            for (int p = 0; p < 4; p++) {
                int ky = kyb + p * 16;
                size_t goff = (size_t)bb * KD * HWP + (size_t)(k0 + ky) * HWP + i0 + i4;
                if (BBF) {
                    u16x4 v = *(const u16x4*)(Bh + goff);
                    Bs[i4 + 0][ky] = (short)v.x;
                    Bs[i4 + 1][ky] = (short)v.y;
                    Bs[i4 + 2][ky] = (short)v.z;
                    Bs[i4 + 3][ky] = (short)v.w;
                } else {
                    f32x4 v = *(const f32x4*)(Bf + goff);
                    Bs[i4 + 0][ky] = f2bf(v.x);
                    Bs[i4 + 1][ky] = f2bf(v.y);
                    Bs[i4 + 2][ky] = f2bf(v.z);
                    Bs[i4 + 3][ky] = f2bf(v.w);
                }
            }
        }
        __syncthreads();
#pragma unroll
        for (int ks = 0; ks < 2; ks++) {
            short8 af0 = *(const short8*)&As[wm + l15][ks * 32 + quad * 8];
            short8 af1 = *(const short8*)&As[wm + 16 + l15][ks * 32 + quad * 8];
            short8 bf0 = *(const short8*)&Bs[wn + l15][ks * 32 + quad * 8];
            short8 bf1 = *(const short8*)&Bs[wn + 16 + l15][ks * 32 + quad * 8];
            acc[0][0] = __builtin_amdgcn_mfma_f32_16x16x32_bf16(af0, bf0, acc[0][0], 0, 0, 0);
            acc[0][1] = __builtin_amdgcn_mfma_f32_16x16x32_bf16(af0, bf1, acc[0][1], 0, 0, 0);
            acc[1][0] = __builtin_amdgcn_mfma_f32_16x16x32_bf16(af1, bf0, acc[1][0], 0, 0, 0);
            acc[1][1] = __builtin_amdgcn_mfma_f32_16x16x32_bf16(af1, bf1, acc[1][1], 0, 0, 0);
        }
    }

    float* outF = (float*)outp;
    unsigned short* outH = (unsigned short*)outp;
#pragma unroll
    for (int im = 0; im < 2; im++) {
#pragma unroll
        for (int r = 0; r < 4; r++) {
            int m = m0 + wm + im * 16 + quad * 4 + r;
            float bv = bias[m];
#pragma unroll
            for (int in_ = 0; in_ < 2; in_++) {
                int n = i0 + wn + in_ * 16 + l15;
                size_t idx = ((size_t)bb * MM + m) * HWP + n;
                float v = acc[im][in_][r] + bv;
                if constexpr (EPI == 1) {
                    float ge = 0.5f * v * (1.0f + erff(v * 0.7071067811865475f));
                    outH[idx] = (unsigned short)f2bf(ge);
                } else if constexpr (EPI == 3) {
                    float vr = v + resid[idx];
                    outF[idx] = vr;
                    out2[idx] = (unsigned short)f2bf(fmaf(vr, bns[m] * invs, bnb[m]));
                } else {
                    outF[idx] = v + resid[idx];
                }
            }
        }
    }
}

extern "C" void kernel_launch(void* const* d_in, const int* in_sizes, int n_in,
                              void* d_out, int out_size, void* d_ws, size_t ws_size,
                              hipStream_t stream) {
    const float* x      = (const float*)d_in[0];
    const float* bn1_g  = (const float*)d_in[1];
    const float* bn1_b  = (const float*)d_in[2];
    const float* bn2_g  = (const float*)d_in[3];
    const float* bn2_b  = (const float*)d_in[4];
    const float* qw     = (const float*)d_in[5];
    const float* kw     = (const float*)d_in[6];
    const float* vw     = (const float*)d_in[7];
    const float* out_w  = (const float*)d_in[8];
    const float* out_b  = (const float*)d_in[9];
    const float* off_dw_w = (const float*)d_in[10];
    const float* off_dw_b = (const float*)d_in[11];
    const float* off_pw_w = (const float*)d_in[12];
    const float* cpb_w1 = (const float*)d_in[13];
    const float* cpb_b1 = (const float*)d_in[14];
    const float* cpb_w2 = (const float*)d_in[15];
    const float* cpb_b2 = (const float*)d_in[16];
    const float* cpb_w3 = (const float*)d_in[17];
    const float* cpb_b3 = (const float*)d_in[18];
    const float* mlp_w1 = (const float*)d_in[19];
    const float* mlp_b1 = (const float*)d_in[20];
    const float* mlp_w2 = (const float*)d_in[21];
    const float* mlp_b2 = (const float*)d_in[22];

    float* ws = (float*)d_ws;
    float* q     = ws + 1048576;      // 1,048,576 floats
    float* vgrid = ws + 2097152;      // 2,048
    float* kk    = ws + 2164736;      // 65,536
    float* vv    = ws + 2230272;      // 65,536
    unsigned short* w2p = (unsigned short*)(ws + 2295808);  // 16,384 bf16
    unsigned short* ao  = (unsigned short*)(ws + 2312192);  // 1,048,576 bf16 (524,288 floats)
    unsigned short* xn2 = (unsigned short*)(ws + 2836480);  // 1,048,576 bf16 (524,288 floats)
    float* xo    = ws + 3360768;      // 1,048,576 floats
    float* h1of  = ws + 4409344;      // bias (1M floats), then h1o bf16 (4M ushorts)
    float* biasb = h1of;
    unsigned short* h1o = (unsigned short*)h1of;
    unsigned short* wp  = (unsigned short*)(ws + 6506496);  // 2,392,064 ushorts
    unsigned short* qwp  = wp;
    unsigned short* owp  = wp + 32768;
    unsigned short* w1p  = wp + 294912;
    unsigned short* w2mp = wp + 1343488;

    hipLaunchKernelGGL(k_wpack, dim3(9408), dim3(256), 0, stream,
                       qw, out_w, mlp_w1, mlp_w2, cpb_w2, wp, w2p);
    hipLaunchKernelGGL(k_qgemm, dim3(256), dim3(256), 0, stream, x, bn1_g, bn1_b, qwp, q);
    hipLaunchKernelGGL(k_off, dim3(1024), dim3(64), 0, stream, q, off_dw_w, off_dw_b, off_pw_w, vgrid);
    hipLaunchKernelGGL(k_skv, dim3(1024), dim3(64), 0, stream, x, bn1_g, bn1_b, vgrid, kw, vw, kk, vv);
    hipLaunchKernelGGL(k_cpb, dim3(2048), dim3(256), 0, stream,
                       vgrid, w2p, cpb_w1, cpb_b1, cpb_b2, cpb_w3, cpb_b3, biasb);
    hipLaunchKernelGGL(k_attn, dim3(256), dim3(256), 0, stream, q, kk, vv, biasb, ao);
    // out projection: M=512, K=512, B=ao bf16, resid=x -> xo (fp32) + xn2 (bf16, BN2 folded)
    k_gemm<3, 512, 8, true><<<dim3(256), dim3(256), 0, stream>>>(
        owp, ao, x, out_b, xo, xn2, bn2_g, bn2_b);
    // MLP1: M=2048, K=512, B=xn2 bf16 (straight copy path), gelu -> h1o (bf16)
    k_gemm<1, 512, 32, true><<<dim3(1024), dim3(256), 0, stream>>>(
        w1p, xn2, nullptr, mlp_b1, h1o, nullptr, nullptr, nullptr);
    // MLP2: M=512, K=2048, B=h1o bf16, resid=xo -> d_out
    k_gemm<2, 2048, 8, true><<<dim3(256), dim3(256), 0, stream>>>(
        w2mp, h1o, xo, mlp_b2, d_out, nullptr, nullptr, nullptr);
}

// Round 10
// 261.961 us; speedup vs baseline: 1.3140x; 1.0538x over previous
//
#include <hip/hip_runtime.h>
#include <hip/hip_bf16.h>
#include <math.h>

// Problem constants
#define BB 2
#define CC 512
#define HH 32
#define WW 32
#define HWP 1024      // H*W
#define GG 8
#define DH 64
#define HD 8
#define WD 8
#define JJ 64         // HD*WD
#define BG 16         // BB*GG
#define EPS 1e-5f

typedef __attribute__((ext_vector_type(8))) short short8;
typedef __attribute__((ext_vector_type(4))) short s16x4;
typedef __attribute__((ext_vector_type(4))) float f32x4;
typedef __attribute__((ext_vector_type(4))) unsigned short u16x4;
typedef __attribute__((ext_vector_type(4))) unsigned int u32x4;

// RNE float -> bf16 bits
static __device__ __forceinline__ short f2bf(float x) {
    unsigned u = __builtin_bit_cast(unsigned, x);
    u += 0x7FFFu + ((u >> 16) & 1u);
    return (short)(u >> 16);
}
static __device__ __forceinline__ float bf2f(unsigned short h) {
    return __builtin_bit_cast(float, (unsigned)h << 16);
}

// ---------------- K0: pre-pack ALL weights to bf16 ----------------
__global__ void k_wpack(const float* __restrict__ qw, const float* __restrict__ ow,
                        const float* __restrict__ w1, const float* __restrict__ w2,
                        const float* __restrict__ cw2, unsigned short* __restrict__ wp,
                        unsigned short* __restrict__ w2p) {
    int idx = blockIdx.x * 256 + threadIdx.x;
    if (idx < 2392064) {
        float v;
        if (idx < 32768) v = qw[idx];
        else if (idx < 294912) v = ow[idx - 32768];
        else if (idx < 1343488) v = w1[idx - 294912];
        else v = w2[idx - 1343488];
        wp[idx] = (unsigned short)f2bf(v);
    } else if (idx < 2408448) {
        int i2 = idx - 2392064;
        int k = i2 >> 7, n = i2 & 127;
        int dest = ((((n >> 4) * 4 + (k >> 5)) * 64) + (((k >> 3) & 3) * 16) + (n & 15)) * 8 + (k & 7);
        w2p[dest] = (unsigned short)f2bf(cw2[i2]);
    }
}

// ---------------- K2: q grouped 1x1 conv via MFMA -> qt[bg][i][ch] bf16 ----------------
__global__ __launch_bounds__(256) void k_qgemm(
    const float* __restrict__ x, const float* __restrict__ g1,
    const float* __restrict__ b1, const unsigned short* __restrict__ qwp,
    unsigned short* __restrict__ qt) {
    __shared__ __align__(16) short As[64][72];
    __shared__ __align__(16) short Bs[64][72];
    int blk = blockIdx.x;
    int bg = blk >> 4, nt = blk & 15;
    int b = bg >> 3, g = bg & 7;
    int i0 = nt * 64;
    int tid = threadIdx.x, lane = tid & 63, wv = tid >> 6;
    int wm = (wv >> 1) * 32, wn = (wv & 1) * 32;
    int l15 = lane & 15, quad = lane >> 4;
    const float invs = 1.0f / sqrtf(1.0f + EPS);
    {
        int c4 = (tid & 15) * 4;
        int ob = tid >> 4;
#pragma unroll
        for (int p = 0; p < 4; p++) {
            int o = ob + p * 16;
            u16x4 v = *(const u16x4*)(qwp + (size_t)(g * 64 + o) * 64 + c4);
            *(u16x4*)&As[o][c4] = v;
        }
    }
    {
        int i4 = (tid & 15) * 4;
        int cb = tid >> 4;
#pragma unroll
        for (int p = 0; p < 4; p++) {
            int c = cb + p * 16;
            f32x4 v = *(const f32x4*)(x + (size_t)(b * CC + g * 64 + c) * HWP + i0 + i4);
            float sc = g1[g * 64 + c] * invs;
            float sh = b1[g * 64 + c];
            Bs[i4 + 0][c] = f2bf(fmaf(v.x, sc, sh));
            Bs[i4 + 1][c] = f2bf(fmaf(v.y, sc, sh));
            Bs[i4 + 2][c] = f2bf(fmaf(v.z, sc, sh));
            Bs[i4 + 3][c] = f2bf(fmaf(v.w, sc, sh));
        }
    }
    __syncthreads();
    f32x4 acc[2][2];
#pragma unroll
    for (int a = 0; a < 2; a++)
#pragma unroll
        for (int c = 0; c < 2; c++) acc[a][c] = (f32x4){0.f, 0.f, 0.f, 0.f};
#pragma unroll
    for (int ks = 0; ks < 2; ks++) {
        short8 af0 = *(const short8*)&As[wm + l15][ks * 32 + quad * 8];
        short8 af1 = *(const short8*)&As[wm + 16 + l15][ks * 32 + quad * 8];
        short8 bf0 = *(const short8*)&Bs[wn + l15][ks * 32 + quad * 8];
        short8 bf1 = *(const short8*)&Bs[wn + 16 + l15][ks * 32 + quad * 8];
        acc[0][0] = __builtin_amdgcn_mfma_f32_16x16x32_bf16(af0, bf0, acc[0][0], 0, 0, 0);
        acc[0][1] = __builtin_amdgcn_mfma_f32_16x16x32_bf16(af0, bf1, acc[0][1], 0, 0, 0);
        acc[1][0] = __builtin_amdgcn_mfma_f32_16x16x32_bf16(af1, bf0, acc[1][0], 0, 0, 0);
        acc[1][1] = __builtin_amdgcn_mfma_f32_16x16x32_bf16(af1, bf1, acc[1][1], 0, 0, 0);
    }
    // transpose via LDS (reuse As) -> coalesced qt[bg][i][ch] bf16 stores
    __syncthreads();
#pragma unroll
    for (int im = 0; im < 2; im++)
#pragma unroll
        for (int r = 0; r < 4; r++) {
            int m = wm + im * 16 + quad * 4 + r;
#pragma unroll
            for (int in_ = 0; in_ < 2; in_++) {
                int n = wn + in_ * 16 + l15;
                As[n][m] = f2bf(acc[im][in_][r]);
            }
        }
    __syncthreads();
    {
        int n = tid >> 2;
        int c0 = (tid & 3) * 16;
        short8 a = *(const short8*)&As[n][c0];
        short8 c = *(const short8*)&As[n][c0 + 8];
        unsigned short* dst = qt + ((size_t)bg * 1024 + i0 + n) * 64 + c0;
        *(short8*)dst = a;
        *(short8*)(dst + 8) = c;
    }
}

// ---------------- K3+K4+K5 fused: offsets -> vgrid -> grid_sample(BN1) -> k/v conv ----------------
// 1024 blocks = bg*64 + (hd*8+wd) = bg*64 + j; 64 threads.
__global__ __launch_bounds__(64) void k_offskv(
    const unsigned short* __restrict__ qt, const float* __restrict__ dww,
    const float* __restrict__ dwb, const float* __restrict__ pw,
    const float* __restrict__ x, const float* __restrict__ g1,
    const float* __restrict__ b1, const float* __restrict__ kw,
    const float* __restrict__ vw, float* __restrict__ vgrid,
    float* __restrict__ kk, float* __restrict__ vv) {
    __shared__ float sm[64];
    int blk = blockIdx.x;
    int bg = blk >> 6;
    int hd = (blk >> 3) & 7;
    int wd = blk & 7;
    int g = bg & 7, b = bg >> 3;
    int ch = threadIdx.x;
    // phase 1: depthwise 6x6 s4 conv on qt (coalesced: lane=ch contiguous)
    const unsigned short* qb = qt + (size_t)bg * 65536;
    float acc = 0.f;
#pragma unroll
    for (int kh = 0; kh < 6; kh++) {
        int hin = hd * 4 - 1 + kh;
        if (hin < 0 || hin >= HH) continue;
#pragma unroll
        for (int kw_ = 0; kw_ < 6; kw_++) {
            int win = wd * 4 - 1 + kw_;
            if (win < 0 || win >= WW) continue;
            acc = fmaf(bf2f(qb[(hin * WW + win) * 64 + ch]), dww[ch * 36 + kh * 6 + kw_], acc);
        }
    }
    acc += dwb[ch];
    float ge = 0.5f * acc * (1.0f + erff(acc * 0.7071067811865475f));
    float p0 = ge * pw[ch];
    float p1 = ge * pw[64 + ch];
#pragma unroll
    for (int off = 32; off; off >>= 1) {
        p0 += __shfl_xor(p0, off);
        p1 += __shfl_xor(p1, off);
    }
    // butterfly leaves full sums on ALL lanes
    float nx = 2.0f * ((float)wd + tanhf(p0) * 4.0f) / 7.0f - 1.0f;
    float ny = 2.0f * ((float)hd + tanhf(p1) * 4.0f) / 7.0f - 1.0f;
    if (ch == 0) {
        vgrid[blk * 2] = nx;
        vgrid[blk * 2 + 1] = ny;
    }
    // phase 2: sample (BN1 folded) into LDS
    {
        int cg = g * 64 + ch;
        const float invs = 1.0f / sqrtf(1.0f + EPS);
        float s = g1[cg] * invs;
        float bv = b1[cg];
        float gx = (nx + 1.0f) * 16.0f - 0.5f;
        float gy = (ny + 1.0f) * 16.0f - 0.5f;
        float x0f = floorf(gx), y0f = floorf(gy);
        float wx = gx - x0f, wy = gy - y0f;
        int x0 = (int)x0f, y0 = (int)y0f;
        const float* im = x + (size_t)(b * CC + cg) * HWP;
        float sx = 0.f, sw = 0.f;
        float w00 = (1 - wx) * (1 - wy), w01 = wx * (1 - wy);
        float w10 = (1 - wx) * wy, w11 = wx * wy;
        if (x0 >= 0 && x0 < WW && y0 >= 0 && y0 < HH)                 { sx += w00 * im[y0 * WW + x0];           sw += w00; }
        if (x0 + 1 >= 0 && x0 + 1 < WW && y0 >= 0 && y0 < HH)         { sx += w01 * im[y0 * WW + x0 + 1];       sw += w01; }
        if (x0 >= 0 && x0 < WW && y0 + 1 >= 0 && y0 + 1 < HH)         { sx += w10 * im[(y0 + 1) * WW + x0];     sw += w10; }
        if (x0 + 1 >= 0 && x0 + 1 < WW && y0 + 1 >= 0 && y0 + 1 < HH) { sx += w11 * im[(y0 + 1) * WW + x0 + 1]; sw += w11; }
        sm[ch] = s * sx + bv * sw;
    }
    __syncthreads();
    // phase 3: k/v grouped conv (thread = output channel)
    int j = blk & 63;
    const float* kwr = kw + (size_t)(g * 64 + ch) * 64;
    const float* vwr = vw + (size_t)(g * 64 + ch) * 64;
    float ak = 0.f, av = 0.f;
#pragma unroll
    for (int c = 0; c < 64; c++) {
        float tv = sm[c];
        ak = fmaf(tv, kwr[c], ak);
        av = fmaf(tv, vwr[c], av);
    }
    kk[(size_t)bg * 4096 + j * 64 + ch] = ak;
    vv[(size_t)bg * 4096 + j * 64 + ch] = av;
}

// ---------------- K6: CPB bias MLP via bf16 MFMA (v5, frozen at ~83us) ----------------
__global__ __launch_bounds__(256) void k_cpb(
    const float* __restrict__ vgrid, const unsigned short* __restrict__ w2p,
    const float* __restrict__ w1, const float* __restrict__ b1,
    const float* __restrict__ b2, const float* __restrict__ w3,
    const float* __restrict__ b3, float* __restrict__ bias) {
    __shared__ __align__(16) short w2fs[16384];
    __shared__ __align__(16) float coef[640];
    int tid = threadIdx.x;
    {
        const u32x4* src = (const u32x4*)w2p;
        u32x4* dst = (u32x4*)w2fs;
        for (int c = tid; c < 2048; c += 256) dst[c] = src[c];
    }
    if (tid < 256) coef[tid] = w1[tid];
    else if (tid < 384) coef[tid] = b1[tid - 256];
    else if (tid < 512) coef[tid] = b2[tid - 384];
    if (tid >= 128 && tid < 256) coef[512 + tid - 128] = w3[tid - 128];
    float bias3 = b3[0];
    __syncthreads();

    int lane = tid & 63;
    int wv = tid >> 6;
    int l15 = lane & 15;
    int quad = lane >> 4;

#pragma unroll 1
    for (int it = 0; it < 4; it++) {
        int p = (blockIdx.x * 4 + it) * 4 + wv;
        int bg = p >> 11;
        int i = (p >> 1) & 1023;
        int jbase = (p & 1) * 32;
        int hi = i >> 5, wi = i & 31;
        float qx = 2.0f * (float)wi / 31.0f - 1.0f;
        float qy = 2.0f * (float)hi / 31.0f - 1.0f;

        int jA = jbase + l15;
        float gkxA = vgrid[(bg * 64 + jA) * 2];
        float gkyA = vgrid[(bg * 64 + jA) * 2 + 1];
        float gkxB = vgrid[(bg * 64 + jA + 16) * 2];
        float gkyB = vgrid[(bg * 64 + jA + 16) * 2 + 1];
        float p0 = qx - gkxA, p1 = qy - gkyA;
        float s0a = copysignf(log1pf(fabsf(p0)), p0);
        float s1a = copysignf(log1pf(fabsf(p1)), p1);
        p0 = qx - gkxB; p1 = qy - gkyB;
        float s0b = copysignf(log1pf(fabsf(p0)), p0);
        float s1b = copysignf(log1pf(fabsf(p1)), p1);

        short8 hA[4], hB[4];
#pragma unroll
        for (int kc = 0; kc < 4; kc++) {
            f32x4 cu0 = *(const f32x4*)&coef[kc * 32 + quad * 8];
            f32x4 cu1 = *(const f32x4*)&coef[kc * 32 + quad * 8 + 4];
            f32x4 cv0 = *(const f32x4*)&coef[128 + kc * 32 + quad * 8];
            f32x4 cv1 = *(const f32x4*)&coef[128 + kc * 32 + quad * 8 + 4];
            f32x4 cb0 = *(const f32x4*)&coef[256 + kc * 32 + quad * 8];
            f32x4 cb1 = *(const f32x4*)&coef[256 + kc * 32 + quad * 8 + 4];
            u32x4 pa, pb;
#pragma unroll
            for (int j2 = 0; j2 < 4; j2++) {
                int e0 = 2 * j2, e1 = 2 * j2 + 1;
                float u0 = (e0 < 4) ? cu0[e0] : cu1[e0 - 4];
                float u1 = (e1 < 4) ? cu0[e1] : cu1[e1 - 4];
                float v0 = (e0 < 4) ? cv0[e0] : cv1[e0 - 4];
                float v1 = (e1 < 4) ? cv0[e1] : cv1[e1 - 4];
                float c0 = (e0 < 4) ? cb0[e0] : cb1[e0 - 4];
                float c1 = (e1 < 4) ? cb0[e1] : cb1[e1 - 4];
                unsigned a0 = __builtin_bit_cast(unsigned,
                    fmaxf(fmaf(s0a, u0, fmaf(s1a, v0, c0)), 0.f)) + 0x8000u;
                unsigned a1 = __builtin_bit_cast(unsigned,
                    fmaxf(fmaf(s0a, u1, fmaf(s1a, v1, c1)), 0.f)) + 0x8000u;
                pa[j2] = __builtin_amdgcn_perm(a1, a0, 0x07060302);
                unsigned b0 = __builtin_bit_cast(unsigned,
                    fmaxf(fmaf(s0b, u0, fmaf(s1b, v0, c0)), 0.f)) + 0x8000u;
                unsigned b1_ = __builtin_bit_cast(unsigned,
                    fmaxf(fmaf(s0b, u1, fmaf(s1b, v1, c1)), 0.f)) + 0x8000u;
                pb[j2] = __builtin_amdgcn_perm(b1_, b0, 0x07060302);
            }
            hA[kc] = __builtin_bit_cast(short8, pa);
            hB[kc] = __builtin_bit_cast(short8, pb);
        }

        float psumA = 0.f, psumB = 0.f;
#pragma unroll 2
        for (int nt = 0; nt < 8; nt++) {
            f32x4 accA = (f32x4){0.f, 0.f, 0.f, 0.f};
            f32x4 accB = (f32x4){0.f, 0.f, 0.f, 0.f};
#pragma unroll
            for (int kc = 0; kc < 4; kc++) {
                short8 af = *(const short8*)(w2fs + (((nt * 4 + kc) * 64) + lane) * 8);
                accA = __builtin_amdgcn_mfma_f32_16x16x32_bf16(af, hA[kc], accA, 0, 0, 0);
                accB = __builtin_amdgcn_mfma_f32_16x16x32_bf16(af, hB[kc], accB, 0, 0, 0);
            }
            f32x4 b2q = *(const f32x4*)&coef[384 + nt * 16 + quad * 4];
            f32x4 w3q = *(const f32x4*)&coef[512 + nt * 16 + quad * 4];
#pragma unroll
            for (int r = 0; r < 4; r++) {
                psumA = fmaf(fmaxf(accA[r] + b2q[r], 0.f), w3q[r], psumA);
                psumB = fmaf(fmaxf(accB[r] + b2q[r], 0.f), w3q[r], psumB);
            }
        }
        psumA += __shfl_xor(psumA, 16);
        psumA += __shfl_xor(psumA, 32);
        psumB += __shfl_xor(psumB, 16);
        psumB += __shfl_xor(psumB, 32);
        if (quad == 0) {
            bias[(size_t)(p * 2 + 0) * 16 + l15] = psumA + bias3;
            bias[(size_t)(p * 2 + 1) * 16 + l15] = psumB + bias3;
        }
    }
}

// ---------------- K7: attention via MFMA (Q from qt bf16; scale folded into S) ----------------
__global__ __launch_bounds__(256) void k_attn(
    const unsigned short* __restrict__ qt, const float* __restrict__ kk,
    const float* __restrict__ vv, const float* __restrict__ bias,
    unsigned short* __restrict__ ao) {
    __shared__ __align__(16) short Ks[64][72];
    __shared__ __align__(16) short Vt[64][72];
    __shared__ __align__(16) short Qs[64][72];
    __shared__ __align__(16) short Ps[4][16][72];
    int blk = blockIdx.x;
    int bg = blk >> 4;
    int chunk = blk & 15;
    int i0 = chunk * 64;
    int b = bg >> 3, g = bg & 7;
    int tid = threadIdx.x, lane = tid & 63, wv = tid >> 6;
    int l15 = lane & 15, quad = lane >> 4;

    const float* kbase = kk + (size_t)bg * 4096;
    const float* vbase = vv + (size_t)bg * 4096;
#pragma unroll
    for (int it = 0; it < 4; it++) {
        int e4 = it * 1024 + tid * 4;
        int j = e4 >> 6, d = e4 & 63;
        f32x4 k4 = *(const f32x4*)(kbase + e4);
        s16x4 s = {f2bf(k4.x), f2bf(k4.y), f2bf(k4.z), f2bf(k4.w)};
        *(s16x4*)&Ks[j][d] = s;
        f32x4 v4 = *(const f32x4*)(vbase + e4);
        Vt[d + 0][j] = f2bf(v4.x);
        Vt[d + 1][j] = f2bf(v4.y);
        Vt[d + 2][j] = f2bf(v4.z);
        Vt[d + 3][j] = f2bf(v4.w);
    }
    {
        const unsigned short* qtb = qt + ((size_t)bg * 1024 + i0) * 64;
#pragma unroll
        for (int it = 0; it < 4; it++) {
            int e4 = it * 1024 + tid * 4;
            int i = e4 >> 6, d = e4 & 63;
            u16x4 v = *(const u16x4*)(qtb + e4);
            *(u16x4*)&Qs[i][d] = v;
        }
    }
    __syncthreads();

    int iw = wv * 16;
    f32x4 Sacc[4];
#pragma unroll
    for (int nt = 0; nt < 4; nt++) Sacc[nt] = (f32x4){0.f, 0.f, 0.f, 0.f};
#pragma unroll
    for (int ks = 0; ks < 2; ks++) {
        short8 aq = *(const short8*)&Qs[iw + l15][quad * 8 + ks * 32];
#pragma unroll
        for (int nt = 0; nt < 4; nt++) {
            short8 bk = *(const short8*)&Ks[nt * 16 + l15][quad * 8 + ks * 32];
            Sacc[nt] = __builtin_amdgcn_mfma_f32_16x16x32_bf16(aq, bk, Sacc[nt], 0, 0, 0);
        }
    }
    const float* bp = bias + ((size_t)bg * 1024 + i0 + iw + quad * 4) * 64 + l15;
    float Sv[4][4];
#pragma unroll
    for (int nt = 0; nt < 4; nt++)
#pragma unroll
        for (int r = 0; r < 4; r++)
            Sv[nt][r] = fmaf(Sacc[nt][r], 0.125f, bp[r * 64 + nt * 16]);
#pragma unroll
    for (int r = 0; r < 4; r++) {
        float m = fmaxf(fmaxf(Sv[0][r], Sv[1][r]), fmaxf(Sv[2][r], Sv[3][r]));
        m = fmaxf(m, __shfl_xor(m, 1));
        m = fmaxf(m, __shfl_xor(m, 2));
        m = fmaxf(m, __shfl_xor(m, 4));
        m = fmaxf(m, __shfl_xor(m, 8));
        float l = 0.f;
#pragma unroll
        for (int nt = 0; nt < 4; nt++) { Sv[nt][r] = expf(Sv[nt][r] - m); l += Sv[nt][r]; }
        l += __shfl_xor(l, 1);
        l += __shfl_xor(l, 2);
        l += __shfl_xor(l, 4);
        l += __shfl_xor(l, 8);
        float inv = 1.0f / l;
#pragma unroll
        for (int nt = 0; nt < 4; nt++)
            Ps[wv][quad * 4 + r][nt * 16 + l15] = f2bf(Sv[nt][r] * inv);
    }
    f32x4 Oacc[4];
#pragma unroll
    for (int nt = 0; nt < 4; nt++) Oacc[nt] = (f32x4){0.f, 0.f, 0.f, 0.f};
#pragma unroll
    for (int ks = 0; ks < 2; ks++) {
        short8 ap = *(const short8*)&Ps[wv][l15][quad * 8 + ks * 32];
#pragma unroll
        for (int nt = 0; nt < 4; nt++) {
            short8 bv = *(const short8*)&Vt[nt * 16 + l15][quad * 8 + ks * 32];
            Oacc[nt] = __builtin_amdgcn_mfma_f32_16x16x32_bf16(ap, bv, Oacc[nt], 0, 0, 0);
        }
    }
    __syncthreads();
#pragma unroll
    for (int nt = 0; nt < 4; nt++) {
        s16x4 o4 = {f2bf(Oacc[nt][0]), f2bf(Oacc[nt][1]), f2bf(Oacc[nt][2]), f2bf(Oacc[nt][3])};
        *(s16x4*)&Qs[nt * 16 + l15][iw + quad * 4] = o4;
    }
    __syncthreads();
    {
        int d = tid >> 2;
        int ic = (tid & 3) * 16;
        short8 a = *(const short8*)&Qs[d][ic];
        short8 c = *(const short8*)&Qs[d][ic + 8];
        unsigned short* dst = ao + (size_t)(b * CC + g * 64 + d) * HWP + i0 + ic;
        *(short8*)dst = a;
        *(short8*)(dst + 8) = c;
    }
}

// ---------------- K8/K10/K11: tiled bf16-MFMA GEMM (A+B bf16, BK-templated) ----------------
// EPI 0/2: +resid fp32. EPI 1: gelu bf16. EPI 3: +resid fp32 AND bf16(BN2) to out2.
template<int EPI, int KD, int BK, int MT>
__global__ __launch_bounds__(256) void k_gemm(
    const unsigned short* __restrict__ A, const unsigned short* __restrict__ Bh,
    const float* __restrict__ resid, const float* __restrict__ bias,
    void* __restrict__ outp, unsigned short* __restrict__ out2,
    const float* __restrict__ bns, const float* __restrict__ bnb) {
    constexpr int MM = MT * 64;
    __shared__ __align__(16) short As[64][BK + 8];
    __shared__ __align__(16) short Bs[64][BK + 8];
    int tid = threadIdx.x;
    int blk = blockIdx.x;
    int mt = blk & (MT - 1);
    int nb = blk / MT;              // 0..31
    int bb = nb >> 4, nt = nb & 15;
    int m0 = mt * 64, i0 = nt * 64;
    int lane = tid & 63, wv = tid >> 6;
    int wm = (wv >> 1) * 32, wn = (wv & 1) * 32;
    int l15 = lane & 15, quad = lane >> 4;
    const unsigned short* Af = A + (size_t)m0 * KD;
    const float invs = 1.0f / sqrtf(1.0f + EPS);

    f32x4 acc[2][2];
#pragma unroll
    for (int a = 0; a < 2; a++)
#pragma unroll
        for (int c = 0; c < 2; c++) acc[a][c] = (f32x4){0.f, 0.f, 0.f, 0.f};

    for (int k0 = 0; k0 < KD; k0 += BK) {
        __syncthreads();
        {
            int kk4 = (tid & (BK / 4 - 1)) * 4;
            int myb = tid / (BK / 4);
            constexpr int RP = 256 / (BK / 4);     // rows per pass
#pragma unroll
            for (int p = 0; p < 64 / RP; p++) {
                int my = myb + p * RP;
                u16x4 v = *(const u16x4*)(Af + (size_t)my * KD + k0 + kk4);
                *(u16x4*)&As[my][kk4] = v;
            }
        }
        {
            int i4 = (tid & 15) * 4;
            int kyb = tid >> 4;
#pragma unroll
            for (int p = 0; p < BK / 16; p++) {
                int ky = kyb + p * 16;
                size_t goff = (size_t)bb * KD * HWP + (size_t)(k0 + ky) * HWP + i0 + i4;
                u16x4 v = *(const u16x4*)(Bh + goff);
                Bs[i4 + 0][ky] = (short)v.x;
                Bs[i4 + 1][ky] = (short)v.y;
                Bs[i4 + 2][ky] = (short)v.z;
                Bs[i4 + 3][ky] = (short)v.w;
            }
        }
        __syncthreads();
#pragma unroll
        for (int ks = 0; ks < BK / 32; ks++) {
            short8 af0 = *(const short8*)&As[wm + l15][ks * 32 + quad * 8];
            short8 af1 = *(const short8*)&As[wm + 16 + l15][ks * 32 + quad * 8];
            short8 bf0 = *(const short8*)&Bs[wn + l15][ks * 32 + quad * 8];
            short8 bf1 = *(const short8*)&Bs[wn + 16 + l15][ks * 32 + quad * 8];
            acc[0][0] = __builtin_amdgcn_mfma_f32_16x16x32_bf16(af0, bf0, acc[0][0], 0, 0, 0);
            acc[0][1] = __builtin_amdgcn_mfma_f32_16x16x32_bf16(af0, bf1, acc[0][1], 0, 0, 0);
            acc[1][0] = __builtin_amdgcn_mfma_f32_16x16x32_bf16(af1, bf0, acc[1][0], 0, 0, 0);
            acc[1][1] = __builtin_amdgcn_mfma_f32_16x16x32_bf16(af1, bf1, acc[1][1], 0, 0, 0);
        }
    }

    float* outF = (float*)outp;
    unsigned short* outH = (unsigned short*)outp;
#pragma unroll
    for (int im = 0; im < 2; im++) {
#pragma unroll
        for (int r = 0; r < 4; r++) {
            int m = m0 + wm + im * 16 + quad * 4 + r;
            float bv = bias[m];
#pragma unroll
            for (int in_ = 0; in_ < 2; in_++) {
                int n = i0 + wn + in_ * 16 + l15;
                size_t idx = ((size_t)bb * MM + m) * HWP + n;
                float v = acc[im][in_][r] + bv;
                if constexpr (EPI == 1) {
                    float ge = 0.5f * v * (1.0f + erff(v * 0.7071067811865475f));
                    outH[idx] = (unsigned short)f2bf(ge);
                } else if constexpr (EPI == 3) {
                    float vr = v + resid[idx];
                    outF[idx] = vr;
                    out2[idx] = (unsigned short)f2bf(fmaf(vr, bns[m] * invs, bnb[m]));
                } else {
                    outF[idx] = v + resid[idx];
                }
            }
        }
    }
}

extern "C" void kernel_launch(void* const* d_in, const int* in_sizes, int n_in,
                              void* d_out, int out_size, void* d_ws, size_t ws_size,
                              hipStream_t stream) {
    const float* x      = (const float*)d_in[0];
    const float* bn1_g  = (const float*)d_in[1];
    const float* bn1_b  = (const float*)d_in[2];
    const float* bn2_g  = (const float*)d_in[3];
    const float* bn2_b  = (const float*)d_in[4];
    const float* qw     = (const float*)d_in[5];
    const float* kw     = (const float*)d_in[6];
    const float* vw     = (const float*)d_in[7];
    const float* out_w  = (const float*)d_in[8];
    const float* out_b  = (const float*)d_in[9];
    const float* off_dw_w = (const float*)d_in[10];
    const float* off_dw_b = (const float*)d_in[11];
    const float* off_pw_w = (const float*)d_in[12];
    const float* cpb_w1 = (const float*)d_in[13];
    const float* cpb_b1 = (const float*)d_in[14];
    const float* cpb_w2 = (const float*)d_in[15];
    const float* cpb_b2 = (const float*)d_in[16];
    const float* cpb_w3 = (const float*)d_in[17];
    const float* cpb_b3 = (const float*)d_in[18];
    const float* mlp_w1 = (const float*)d_in[19];
    const float* mlp_b1 = (const float*)d_in[20];
    const float* mlp_w2 = (const float*)d_in[21];
    const float* mlp_b2 = (const float*)d_in[22];

    float* ws = (float*)d_ws;
    unsigned short* qt = (unsigned short*)(ws + 1048576);   // 1,048,576 bf16 (524,288 floats)
    float* vgrid = ws + 2097152;      // 2,048
    float* kk    = ws + 2164736;      // 65,536
    float* vv    = ws + 2230272;      // 65,536
    unsigned short* w2p = (unsigned short*)(ws + 2295808);  // 16,384 bf16
    unsigned short* ao  = (unsigned short*)(ws + 2312192);  // 1,048,576 bf16
    unsigned short* xn2 = (unsigned short*)(ws + 2836480);  // 1,048,576 bf16
    float* xo    = ws + 3360768;      // 1,048,576 floats
    float* h1of  = ws + 4409344;      // bias (1M floats), then h1o bf16 (4M ushorts)
    float* biasb = h1of;
    unsigned short* h1o = (unsigned short*)h1of;
    unsigned short* wp  = (unsigned short*)(ws + 6506496);  // 2,392,064 ushorts
    unsigned short* qwp  = wp;
    unsigned short* owp  = wp + 32768;
    unsigned short* w1p  = wp + 294912;
    unsigned short* w2mp = wp + 1343488;

    hipLaunchKernelGGL(k_wpack, dim3(9408), dim3(256), 0, stream,
                       qw, out_w, mlp_w1, mlp_w2, cpb_w2, wp, w2p);
    hipLaunchKernelGGL(k_qgemm, dim3(256), dim3(256), 0, stream, x, bn1_g, bn1_b, qwp, qt);
    hipLaunchKernelGGL(k_offskv, dim3(1024), dim3(64), 0, stream,
                       qt, off_dw_w, off_dw_b, off_pw_w, x, bn1_g, bn1_b, kw, vw,
                       vgrid, kk, vv);
    hipLaunchKernelGGL(k_cpb, dim3(2048), dim3(256), 0, stream,
                       vgrid, w2p, cpb_w1, cpb_b1, cpb_b2, cpb_w3, cpb_b3, biasb);
    hipLaunchKernelGGL(k_attn, dim3(256), dim3(256), 0, stream, qt, kk, vv, biasb, ao);
    // out projection: M=512, K=512 (BK=128), B=ao bf16, resid=x -> xo + xn2(BN2 bf16)
    k_gemm<3, 512, 128, 8><<<dim3(256), dim3(256), 0, stream>>>(
        owp, ao, x, out_b, xo, xn2, bn2_g, bn2_b);
    // MLP1: M=2048, K=512 (BK=128), B=xn2 bf16, gelu -> h1o bf16
    k_gemm<1, 512, 128, 32><<<dim3(1024), dim3(256), 0, stream>>>(
        w1p, xn2, nullptr, mlp_b1, h1o, nullptr, nullptr, nullptr);
    // MLP2: M=512, K=2048 (BK=128), B=h1o bf16, resid=xo -> d_out
    k_gemm<2, 2048, 128, 8><<<dim3(256), dim3(256), 0, stream>>>(
        w2mp, h1o, xo, mlp_b2, d_out, nullptr, nullptr, nullptr);
}

// Round 11
// 256.349 us; speedup vs baseline: 1.3428x; 1.0219x over previous
//
#include <hip/hip_runtime.h>
#include <hip/hip_bf16.h>
#include <math.h>

// Problem constants
#define BB 2
#define CC 512
#define HH 32
#define WW 32
#define HWP 1024      // H*W
#define GG 8
#define DH 64
#define HD 8
#define WD 8
#define JJ 64         // HD*WD
#define BG 16         // BB*GG
#define EPS 1e-5f

typedef __attribute__((ext_vector_type(8))) short short8;
typedef __attribute__((ext_vector_type(4))) short s16x4;
typedef __attribute__((ext_vector_type(4))) float f32x4;
typedef __attribute__((ext_vector_type(4))) unsigned short u16x4;
typedef __attribute__((ext_vector_type(4))) unsigned int u32x4;

// RNE float -> bf16 bits
static __device__ __forceinline__ short f2bf(float x) {
    unsigned u = __builtin_bit_cast(unsigned, x);
    u += 0x7FFFu + ((u >> 16) & 1u);
    return (short)(u >> 16);
}
static __device__ __forceinline__ float bf2f(unsigned short h) {
    return __builtin_bit_cast(float, (unsigned)h << 16);
}

// ---------------- K0: pre-pack ALL weights to bf16 ----------------
__global__ void k_wpack(const float* __restrict__ qw, const float* __restrict__ ow,
                        const float* __restrict__ w1, const float* __restrict__ w2,
                        const float* __restrict__ cw2, unsigned short* __restrict__ wp,
                        unsigned short* __restrict__ w2p) {
    int idx = blockIdx.x * 256 + threadIdx.x;
    if (idx < 2392064) {
        float v;
        if (idx < 32768) v = qw[idx];
        else if (idx < 294912) v = ow[idx - 32768];
        else if (idx < 1343488) v = w1[idx - 294912];
        else v = w2[idx - 1343488];
        wp[idx] = (unsigned short)f2bf(v);
    } else if (idx < 2408448) {
        int i2 = idx - 2392064;
        int k = i2 >> 7, n = i2 & 127;
        int dest = ((((n >> 4) * 4 + (k >> 5)) * 64) + (((k >> 3) & 3) * 16) + (n & 15)) * 8 + (k & 7);
        w2p[dest] = (unsigned short)f2bf(cw2[i2]);
    }
}

// ---------------- K2: q grouped 1x1 conv via MFMA -> qt[bg][i][ch] bf16 ----------------
__global__ __launch_bounds__(256) void k_qgemm(
    const float* __restrict__ x, const float* __restrict__ g1,
    const float* __restrict__ b1, const unsigned short* __restrict__ qwp,
    unsigned short* __restrict__ qt) {
    __shared__ __align__(16) short As[64][72];
    __shared__ __align__(16) short Bs[64][72];
    int blk = blockIdx.x;
    int bg = blk >> 4, nt = blk & 15;
    int b = bg >> 3, g = bg & 7;
    int i0 = nt * 64;
    int tid = threadIdx.x, lane = tid & 63, wv = tid >> 6;
    int wm = (wv >> 1) * 32, wn = (wv & 1) * 32;
    int l15 = lane & 15, quad = lane >> 4;
    const float invs = 1.0f / sqrtf(1.0f + EPS);
    {
        int c4 = (tid & 15) * 4;
        int ob = tid >> 4;
#pragma unroll
        for (int p = 0; p < 4; p++) {
            int o = ob + p * 16;
            u16x4 v = *(const u16x4*)(qwp + (size_t)(g * 64 + o) * 64 + c4);
            *(u16x4*)&As[o][c4] = v;
        }
    }
    {
        int i4 = (tid & 15) * 4;
        int cb = tid >> 4;
#pragma unroll
        for (int p = 0; p < 4; p++) {
            int c = cb + p * 16;
            f32x4 v = *(const f32x4*)(x + (size_t)(b * CC + g * 64 + c) * HWP + i0 + i4);
            float sc = g1[g * 64 + c] * invs;
            float sh = b1[g * 64 + c];
            Bs[i4 + 0][c] = f2bf(fmaf(v.x, sc, sh));
            Bs[i4 + 1][c] = f2bf(fmaf(v.y, sc, sh));
            Bs[i4 + 2][c] = f2bf(fmaf(v.z, sc, sh));
            Bs[i4 + 3][c] = f2bf(fmaf(v.w, sc, sh));
        }
    }
    __syncthreads();
    f32x4 acc[2][2];
#pragma unroll
    for (int a = 0; a < 2; a++)
#pragma unroll
        for (int c = 0; c < 2; c++) acc[a][c] = (f32x4){0.f, 0.f, 0.f, 0.f};
#pragma unroll
    for (int ks = 0; ks < 2; ks++) {
        short8 af0 = *(const short8*)&As[wm + l15][ks * 32 + quad * 8];
        short8 af1 = *(const short8*)&As[wm + 16 + l15][ks * 32 + quad * 8];
        short8 bf0 = *(const short8*)&Bs[wn + l15][ks * 32 + quad * 8];
        short8 bf1 = *(const short8*)&Bs[wn + 16 + l15][ks * 32 + quad * 8];
        acc[0][0] = __builtin_amdgcn_mfma_f32_16x16x32_bf16(af0, bf0, acc[0][0], 0, 0, 0);
        acc[0][1] = __builtin_amdgcn_mfma_f32_16x16x32_bf16(af0, bf1, acc[0][1], 0, 0, 0);
        acc[1][0] = __builtin_amdgcn_mfma_f32_16x16x32_bf16(af1, bf0, acc[1][0], 0, 0, 0);
        acc[1][1] = __builtin_amdgcn_mfma_f32_16x16x32_bf16(af1, bf1, acc[1][1], 0, 0, 0);
    }
    // transpose via LDS (reuse As) -> coalesced qt[bg][i][ch] bf16 stores
    __syncthreads();
#pragma unroll
    for (int im = 0; im < 2; im++)
#pragma unroll
        for (int r = 0; r < 4; r++) {
            int m = wm + im * 16 + quad * 4 + r;
#pragma unroll
            for (int in_ = 0; in_ < 2; in_++) {
                int n = wn + in_ * 16 + l15;
                As[n][m] = f2bf(acc[im][in_][r]);
            }
        }
    __syncthreads();
    {
        int n = tid >> 2;
        int c0 = (tid & 3) * 16;
        short8 a = *(const short8*)&As[n][c0];
        short8 c = *(const short8*)&As[n][c0 + 8];
        unsigned short* dst = qt + ((size_t)bg * 1024 + i0 + n) * 64 + c0;
        *(short8*)dst = a;
        *(short8*)(dst + 8) = c;
    }
}

// ---------------- K3+K4+K5 fused: offsets -> vgrid -> grid_sample(BN1) -> k/v conv ----------------
__global__ __launch_bounds__(64) void k_offskv(
    const unsigned short* __restrict__ qt, const float* __restrict__ dww,
    const float* __restrict__ dwb, const float* __restrict__ pw,
    const float* __restrict__ x, const float* __restrict__ g1,
    const float* __restrict__ b1, const float* __restrict__ kw,
    const float* __restrict__ vw, float* __restrict__ vgrid,
    float* __restrict__ kk, float* __restrict__ vv) {
    __shared__ float sm[64];
    int blk = blockIdx.x;
    int bg = blk >> 6;
    int hd = (blk >> 3) & 7;
    int wd = blk & 7;
    int g = bg & 7, b = bg >> 3;
    int ch = threadIdx.x;
    const unsigned short* qb = qt + (size_t)bg * 65536;
    float acc = 0.f;
#pragma unroll
    for (int kh = 0; kh < 6; kh++) {
        int hin = hd * 4 - 1 + kh;
        if (hin < 0 || hin >= HH) continue;
#pragma unroll
        for (int kw_ = 0; kw_ < 6; kw_++) {
            int win = wd * 4 - 1 + kw_;
            if (win < 0 || win >= WW) continue;
            acc = fmaf(bf2f(qb[(hin * WW + win) * 64 + ch]), dww[ch * 36 + kh * 6 + kw_], acc);
        }
    }
    acc += dwb[ch];
    float ge = 0.5f * acc * (1.0f + erff(acc * 0.7071067811865475f));
    float p0 = ge * pw[ch];
    float p1 = ge * pw[64 + ch];
#pragma unroll
    for (int off = 32; off; off >>= 1) {
        p0 += __shfl_xor(p0, off);
        p1 += __shfl_xor(p1, off);
    }
    float nx = 2.0f * ((float)wd + tanhf(p0) * 4.0f) / 7.0f - 1.0f;
    float ny = 2.0f * ((float)hd + tanhf(p1) * 4.0f) / 7.0f - 1.0f;
    if (ch == 0) {
        vgrid[blk * 2] = nx;
        vgrid[blk * 2 + 1] = ny;
    }
    {
        int cg = g * 64 + ch;
        const float invs = 1.0f / sqrtf(1.0f + EPS);
        float s = g1[cg] * invs;
        float bv = b1[cg];
        float gx = (nx + 1.0f) * 16.0f - 0.5f;
        float gy = (ny + 1.0f) * 16.0f - 0.5f;
        float x0f = floorf(gx), y0f = floorf(gy);
        float wx = gx - x0f, wy = gy - y0f;
        int x0 = (int)x0f, y0 = (int)y0f;
        const float* im = x + (size_t)(b * CC + cg) * HWP;
        float sx = 0.f, sw = 0.f;
        float w00 = (1 - wx) * (1 - wy), w01 = wx * (1 - wy);
        float w10 = (1 - wx) * wy, w11 = wx * wy;
        if (x0 >= 0 && x0 < WW && y0 >= 0 && y0 < HH)                 { sx += w00 * im[y0 * WW + x0];           sw += w00; }
        if (x0 + 1 >= 0 && x0 + 1 < WW && y0 >= 0 && y0 < HH)         { sx += w01 * im[y0 * WW + x0 + 1];       sw += w01; }
        if (x0 >= 0 && x0 < WW && y0 + 1 >= 0 && y0 + 1 < HH)         { sx += w10 * im[(y0 + 1) * WW + x0];     sw += w10; }
        if (x0 + 1 >= 0 && x0 + 1 < WW && y0 + 1 >= 0 && y0 + 1 < HH) { sx += w11 * im[(y0 + 1) * WW + x0 + 1]; sw += w11; }
        sm[ch] = s * sx + bv * sw;
    }
    __syncthreads();
    int j = blk & 63;
    const float* kwr = kw + (size_t)(g * 64 + ch) * 64;
    const float* vwr = vw + (size_t)(g * 64 + ch) * 64;
    float ak = 0.f, av = 0.f;
#pragma unroll
    for (int c = 0; c < 64; c++) {
        float tv = sm[c];
        ak = fmaf(tv, kwr[c], ak);
        av = fmaf(tv, vwr[c], av);
    }
    kk[(size_t)bg * 4096 + j * 64 + ch] = ak;
    vv[(size_t)bg * 4096 + j * 64 + ch] = av;
}

// ---------------- K6: CPB bias MLP via bf16 MFMA (v6: LDS exactly 32KB, coef from global L1) ----------------
// cofs = (p >> 20) is 0 at runtime (p < 32768) but compiler-opaque: prevents
// LICM from hoisting the 24 coef loads into ~96 VGPRs (r4 lesson) while
// keeping LDS at 32768 -> 5 blocks/CU (r7's spill came from forced
// __launch_bounds__, which is deliberately absent here).
__global__ __launch_bounds__(256) void k_cpb(
    const float* __restrict__ vgrid, const unsigned short* __restrict__ w2p,
    const float* __restrict__ w1, const float* __restrict__ b1,
    const float* __restrict__ b2, const float* __restrict__ w3,
    const float* __restrict__ b3, float* __restrict__ bias) {
    __shared__ __align__(16) short w2fs[16384];   // exactly 32768 B
    int tid = threadIdx.x;
    {
        const u32x4* src = (const u32x4*)w2p;
        u32x4* dst = (u32x4*)w2fs;
        for (int c = tid; c < 2048; c += 256) dst[c] = src[c];
    }
    float bias3 = b3[0];
    __syncthreads();

    int lane = tid & 63;
    int wv = tid >> 6;
    int l15 = lane & 15;
    int quad = lane >> 4;

#pragma unroll 1
    for (int it = 0; it < 4; it++) {
        int p = (blockIdx.x * 4 + it) * 4 + wv;
        int cofs = (int)((unsigned)p >> 20);   // runtime 0, compiler-opaque
        int bg = p >> 11;
        int i = (p >> 1) & 1023;
        int jbase = (p & 1) * 32;
        int hi = i >> 5, wi = i & 31;
        float qx = 2.0f * (float)wi / 31.0f - 1.0f;
        float qy = 2.0f * (float)hi / 31.0f - 1.0f;

        int jA = jbase + l15;
        float gkxA = vgrid[(bg * 64 + jA) * 2];
        float gkyA = vgrid[(bg * 64 + jA) * 2 + 1];
        float gkxB = vgrid[(bg * 64 + jA + 16) * 2];
        float gkyB = vgrid[(bg * 64 + jA + 16) * 2 + 1];
        float p0 = qx - gkxA, p1 = qy - gkyA;
        float s0a = copysignf(log1pf(fabsf(p0)), p0);
        float s1a = copysignf(log1pf(fabsf(p1)), p1);
        p0 = qx - gkxB; p1 = qy - gkyB;
        float s0b = copysignf(log1pf(fabsf(p0)), p0);
        float s1b = copysignf(log1pf(fabsf(p1)), p1);

        short8 hA[4], hB[4];
#pragma unroll
        for (int kc = 0; kc < 4; kc++) {
            f32x4 cu0 = *(const f32x4*)(w1 + cofs + kc * 32 + quad * 8);
            f32x4 cu1 = *(const f32x4*)(w1 + cofs + kc * 32 + quad * 8 + 4);
            f32x4 cv0 = *(const f32x4*)(w1 + cofs + 128 + kc * 32 + quad * 8);
            f32x4 cv1 = *(const f32x4*)(w1 + cofs + 128 + kc * 32 + quad * 8 + 4);
            f32x4 cb0 = *(const f32x4*)(b1 + cofs + kc * 32 + quad * 8);
            f32x4 cb1 = *(const f32x4*)(b1 + cofs + kc * 32 + quad * 8 + 4);
            u32x4 pa, pb;
#pragma unroll
            for (int j2 = 0; j2 < 4; j2++) {
                int e0 = 2 * j2, e1 = 2 * j2 + 1;
                float u0 = (e0 < 4) ? cu0[e0] : cu1[e0 - 4];
                float u1 = (e1 < 4) ? cu0[e1] : cu1[e1 - 4];
                float v0 = (e0 < 4) ? cv0[e0] : cv1[e0 - 4];
                float v1 = (e1 < 4) ? cv0[e1] : cv1[e1 - 4];
                float c0 = (e0 < 4) ? cb0[e0] : cb1[e0 - 4];
                float c1 = (e1 < 4) ? cb0[e1] : cb1[e1 - 4];
                unsigned a0 = __builtin_bit_cast(unsigned,
                    fmaxf(fmaf(s0a, u0, fmaf(s1a, v0, c0)), 0.f)) + 0x8000u;
                unsigned a1 = __builtin_bit_cast(unsigned,
                    fmaxf(fmaf(s0a, u1, fmaf(s1a, v1, c1)), 0.f)) + 0x8000u;
                pa[j2] = __builtin_amdgcn_perm(a1, a0, 0x07060302);
                unsigned b0 = __builtin_bit_cast(unsigned,
                    fmaxf(fmaf(s0b, u0, fmaf(s1b, v0, c0)), 0.f)) + 0x8000u;
                unsigned b1_ = __builtin_bit_cast(unsigned,
                    fmaxf(fmaf(s0b, u1, fmaf(s1b, v1, c1)), 0.f)) + 0x8000u;
                pb[j2] = __builtin_amdgcn_perm(b1_, b0, 0x07060302);
            }
            hA[kc] = __builtin_bit_cast(short8, pa);
            hB[kc] = __builtin_bit_cast(short8, pb);
        }

        float psumA = 0.f, psumB = 0.f;
#pragma unroll 2
        for (int nt = 0; nt < 8; nt++) {
            f32x4 accA = (f32x4){0.f, 0.f, 0.f, 0.f};
            f32x4 accB = (f32x4){0.f, 0.f, 0.f, 0.f};
#pragma unroll
            for (int kc = 0; kc < 4; kc++) {
                short8 af = *(const short8*)(w2fs + (((nt * 4 + kc) * 64) + lane) * 8);
                accA = __builtin_amdgcn_mfma_f32_16x16x32_bf16(af, hA[kc], accA, 0, 0, 0);
                accB = __builtin_amdgcn_mfma_f32_16x16x32_bf16(af, hB[kc], accB, 0, 0, 0);
            }
            f32x4 b2q = *(const f32x4*)(b2 + cofs + nt * 16 + quad * 4);
            f32x4 w3q = *(const f32x4*)(w3 + cofs + nt * 16 + quad * 4);
#pragma unroll
            for (int r = 0; r < 4; r++) {
                psumA = fmaf(fmaxf(accA[r] + b2q[r], 0.f), w3q[r], psumA);
                psumB = fmaf(fmaxf(accB[r] + b2q[r], 0.f), w3q[r], psumB);
            }
        }
        psumA += __shfl_xor(psumA, 16);
        psumA += __shfl_xor(psumA, 32);
        psumB += __shfl_xor(psumB, 16);
        psumB += __shfl_xor(psumB, 32);
        if (quad == 0) {
            bias[(size_t)(p * 2 + 0) * 16 + l15] = psumA + bias3;
            bias[(size_t)(p * 2 + 1) * 16 + l15] = psumB + bias3;
        }
    }
}

// ---------------- K7: attention via MFMA (Q from qt bf16; scale folded into S) ----------------
__global__ __launch_bounds__(256) void k_attn(
    const unsigned short* __restrict__ qt, const float* __restrict__ kk,
    const float* __restrict__ vv, const float* __restrict__ bias,
    unsigned short* __restrict__ ao) {
    __shared__ __align__(16) short Ks[64][72];
    __shared__ __align__(16) short Vt[64][72];
    __shared__ __align__(16) short Qs[64][72];
    __shared__ __align__(16) short Ps[4][16][72];
    int blk = blockIdx.x;
    int bg = blk >> 4;
    int chunk = blk & 15;
    int i0 = chunk * 64;
    int b = bg >> 3, g = bg & 7;
    int tid = threadIdx.x, lane = tid & 63, wv = tid >> 6;
    int l15 = lane & 15, quad = lane >> 4;

    const float* kbase = kk + (size_t)bg * 4096;
    const float* vbase = vv + (size_t)bg * 4096;
#pragma unroll
    for (int it = 0; it < 4; it++) {
        int e4 = it * 1024 + tid * 4;
        int j = e4 >> 6, d = e4 & 63;
        f32x4 k4 = *(const f32x4*)(kbase + e4);
        s16x4 s = {f2bf(k4.x), f2bf(k4.y), f2bf(k4.z), f2bf(k4.w)};
        *(s16x4*)&Ks[j][d] = s;
        f32x4 v4 = *(const f32x4*)(vbase + e4);
        Vt[d + 0][j] = f2bf(v4.x);
        Vt[d + 1][j] = f2bf(v4.y);
        Vt[d + 2][j] = f2bf(v4.z);
        Vt[d + 3][j] = f2bf(v4.w);
    }
    {
        const unsigned short* qtb = qt + ((size_t)bg * 1024 + i0) * 64;
#pragma unroll
        for (int it = 0; it < 4; it++) {
            int e4 = it * 1024 + tid * 4;
            int i = e4 >> 6, d = e4 & 63;
            u16x4 v = *(const u16x4*)(qtb + e4);
            *(u16x4*)&Qs[i][d] = v;
        }
    }
    __syncthreads();

    int iw = wv * 16;
    f32x4 Sacc[4];
#pragma unroll
    for (int nt = 0; nt < 4; nt++) Sacc[nt] = (f32x4){0.f, 0.f, 0.f, 0.f};
#pragma unroll
    for (int ks = 0; ks < 2; ks++) {
        short8 aq = *(const short8*)&Qs[iw + l15][quad * 8 + ks * 32];
#pragma unroll
        for (int nt = 0; nt < 4; nt++) {
            short8 bk = *(const short8*)&Ks[nt * 16 + l15][quad * 8 + ks * 32];
            Sacc[nt] = __builtin_amdgcn_mfma_f32_16x16x32_bf16(aq, bk, Sacc[nt], 0, 0, 0);
        }
    }
    const float* bp = bias + ((size_t)bg * 1024 + i0 + iw + quad * 4) * 64 + l15;
    float Sv[4][4];
#pragma unroll
    for (int nt = 0; nt < 4; nt++)
#pragma unroll
        for (int r = 0; r < 4; r++)
            Sv[nt][r] = fmaf(Sacc[nt][r], 0.125f, bp[r * 64 + nt * 16]);
#pragma unroll
    for (int r = 0; r < 4; r++) {
        float m = fmaxf(fmaxf(Sv[0][r], Sv[1][r]), fmaxf(Sv[2][r], Sv[3][r]));
        m = fmaxf(m, __shfl_xor(m, 1));
        m = fmaxf(m, __shfl_xor(m, 2));
        m = fmaxf(m, __shfl_xor(m, 4));
        m = fmaxf(m, __shfl_xor(m, 8));
        float l = 0.f;
#pragma unroll
        for (int nt = 0; nt < 4; nt++) { Sv[nt][r] = expf(Sv[nt][r] - m); l += Sv[nt][r]; }
        l += __shfl_xor(l, 1);
        l += __shfl_xor(l, 2);
        l += __shfl_xor(l, 4);
        l += __shfl_xor(l, 8);
        float inv = 1.0f / l;
#pragma unroll
        for (int nt = 0; nt < 4; nt++)
            Ps[wv][quad * 4 + r][nt * 16 + l15] = f2bf(Sv[nt][r] * inv);
    }
    f32x4 Oacc[4];
#pragma unroll
    for (int nt = 0; nt < 4; nt++) Oacc[nt] = (f32x4){0.f, 0.f, 0.f, 0.f};
#pragma unroll
    for (int ks = 0; ks < 2; ks++) {
        short8 ap = *(const short8*)&Ps[wv][l15][quad * 8 + ks * 32];
#pragma unroll
        for (int nt = 0; nt < 4; nt++) {
            short8 bv = *(const short8*)&Vt[nt * 16 + l15][quad * 8 + ks * 32];
            Oacc[nt] = __builtin_amdgcn_mfma_f32_16x16x32_bf16(ap, bv, Oacc[nt], 0, 0, 0);
        }
    }
    __syncthreads();
#pragma unroll
    for (int nt = 0; nt < 4; nt++) {
        s16x4 o4 = {f2bf(Oacc[nt][0]), f2bf(Oacc[nt][1]), f2bf(Oacc[nt][2]), f2bf(Oacc[nt][3])};
        *(s16x4*)&Qs[nt * 16 + l15][iw + quad * 4] = o4;
    }
    __syncthreads();
    {
        int d = tid >> 2;
        int ic = (tid & 3) * 16;
        short8 a = *(const short8*)&Qs[d][ic];
        short8 c = *(const short8*)&Qs[d][ic + 8];
        unsigned short* dst = ao + (size_t)(b * CC + g * 64 + d) * HWP + i0 + ic;
        *(short8*)dst = a;
        *(short8*)(dst + 8) = c;
    }
}

// ---------------- K8/K10/K11: tiled bf16-MFMA GEMM (A+B bf16, BK-templated) ----------------
// EPI 0/2: +resid fp32. EPI 1: gelu bf16. EPI 3: +resid fp32 AND bf16(BN2) to out2.
template<int EPI, int KD, int BK, int MT>
__global__ __launch_bounds__(256) void k_gemm(
    const unsigned short* __restrict__ A, const unsigned short* __restrict__ Bh,
    const float* __restrict__ resid, const float* __restrict__ bias,
    void* __restrict__ outp, unsigned short* __restrict__ out2,
    const float* __restrict__ bns, const float* __restrict__ bnb) {
    constexpr int MM = MT * 64;
    __shared__ __align__(16) short As[64][BK + 8];
    __shared__ __align__(16) short Bs[64][BK + 8];
    int tid = threadIdx.x;
    int blk = blockIdx.x;
    int mt = blk & (MT - 1);
    int nb = blk / MT;              // 0..31
    int bb = nb >> 4, nt = nb & 15;
    int m0 = mt * 64, i0 = nt * 64;
    int lane = tid & 63, wv = tid >> 6;
    int wm = (wv >> 1) * 32, wn = (wv & 1) * 32;
    int l15 = lane & 15, quad = lane >> 4;
    const unsigned short* Af = A + (size_t)m0 * KD;
    const float invs = 1.0f / sqrtf(1.0f + EPS);

    f32x4 acc[2][2];
#pragma unroll
    for (int a = 0; a < 2; a++)
#pragma unroll
        for (int c = 0; c < 2; c++) acc[a][c] = (f32x4){0.f, 0.f, 0.f, 0.f};

    for (int k0 = 0; k0 < KD; k0 += BK) {
        __syncthreads();
        {
            int kk4 = (tid & (BK / 4 - 1)) * 4;
            int myb = tid / (BK / 4);
            constexpr int RP = 256 / (BK / 4);     // rows per pass
#pragma unroll
            for (int p = 0; p < 64 / RP; p++) {
                int my = myb + p * RP;
                u16x4 v = *(const u16x4*)(Af + (size_t)my * KD + k0 + kk4);
                *(u16x4*)&As[my][kk4] = v;
            }
        }
        {
            int i4 = (tid & 15) * 4;
            int kyb = tid >> 4;
#pragma unroll
            for (int p = 0; p < BK / 16; p++) {
                int ky = kyb + p * 16;
                size_t goff = (size_t)bb * KD * HWP + (size_t)(k0 + ky) * HWP + i0 + i4;
                u16x4 v = *(const u16x4*)(Bh + goff);
                Bs[i4 + 0][ky] = (short)v.x;
                Bs[i4 + 1][ky] = (short)v.y;
                Bs[i4 + 2][ky] = (short)v.z;
                Bs[i4 + 3][ky] = (short)v.w;
            }
        }
        __syncthreads();
#pragma unroll
        for (int ks = 0; ks < BK / 32; ks++) {
            short8 af0 = *(const short8*)&As[wm + l15][ks * 32 + quad * 8];
            short8 af1 = *(const short8*)&As[wm + 16 + l15][ks * 32 + quad * 8];
            short8 bf0 = *(const short8*)&Bs[wn + l15][ks * 32 + quad * 8];
            short8 bf1 = *(const short8*)&Bs[wn + 16 + l15][ks * 32 + quad * 8];
            acc[0][0] = __builtin_amdgcn_mfma_f32_16x16x32_bf16(af0, bf0, acc[0][0], 0, 0, 0);
            acc[0][1] = __builtin_amdgcn_mfma_f32_16x16x32_bf16(af0, bf1, acc[0][1], 0, 0, 0);
            acc[1][0] = __builtin_amdgcn_mfma_f32_16x16x32_bf16(af1, bf0, acc[1][0], 0, 0, 0);
            acc[1][1] = __builtin_amdgcn_mfma_f32_16x16x32_bf16(af1, bf1, acc[1][1], 0, 0, 0);
        }
    }

    float* outF = (float*)outp;
    unsigned short* outH = (unsigned short*)outp;
#pragma unroll
    for (int im = 0; im < 2; im++) {
#pragma unroll
        for (int r = 0; r < 4; r++) {
            int m = m0 + wm + im * 16 + quad * 4 + r;
            float bv = bias[m];
#pragma unroll
            for (int in_ = 0; in_ < 2; in_++) {
                int n = i0 + wn + in_ * 16 + l15;
                size_t idx = ((size_t)bb * MM + m) * HWP + n;
                float v = acc[im][in_][r] + bv;
                if constexpr (EPI == 1) {
                    float ge = 0.5f * v * (1.0f + erff(v * 0.7071067811865475f));
                    outH[idx] = (unsigned short)f2bf(ge);
                } else if constexpr (EPI == 3) {
                    float vr = v + resid[idx];
                    outF[idx] = vr;
                    out2[idx] = (unsigned short)f2bf(fmaf(vr, bns[m] * invs, bnb[m]));
                } else {
                    outF[idx] = v + resid[idx];
                }
            }
        }
    }
}

extern "C" void kernel_launch(void* const* d_in, const int* in_sizes, int n_in,
                              void* d_out, int out_size, void* d_ws, size_t ws_size,
                              hipStream_t stream) {
    const float* x      = (const float*)d_in[0];
    const float* bn1_g  = (const float*)d_in[1];
    const float* bn1_b  = (const float*)d_in[2];
    const float* bn2_g  = (const float*)d_in[3];
    const float* bn2_b  = (const float*)d_in[4];
    const float* qw     = (const float*)d_in[5];
    const float* kw     = (const float*)d_in[6];
    const float* vw     = (const float*)d_in[7];
    const float* out_w  = (const float*)d_in[8];
    const float* out_b  = (const float*)d_in[9];
    const float* off_dw_w = (const float*)d_in[10];
    const float* off_dw_b = (const float*)d_in[11];
    const float* off_pw_w = (const float*)d_in[12];
    const float* cpb_w1 = (const float*)d_in[13];
    const float* cpb_b1 = (const float*)d_in[14];
    const float* cpb_w2 = (const float*)d_in[15];
    const float* cpb_b2 = (const float*)d_in[16];
    const float* cpb_w3 = (const float*)d_in[17];
    const float* cpb_b3 = (const float*)d_in[18];
    const float* mlp_w1 = (const float*)d_in[19];
    const float* mlp_b1 = (const float*)d_in[20];
    const float* mlp_w2 = (const float*)d_in[21];
    const float* mlp_b2 = (const float*)d_in[22];

    float* ws = (float*)d_ws;
    unsigned short* qt = (unsigned short*)(ws + 1048576);   // 1,048,576 bf16
    float* vgrid = ws + 2097152;      // 2,048
    float* kk    = ws + 2164736;      // 65,536
    float* vv    = ws + 2230272;      // 65,536
    unsigned short* w2p = (unsigned short*)(ws + 2295808);  // 16,384 bf16
    unsigned short* ao  = (unsigned short*)(ws + 2312192);  // 1,048,576 bf16
    unsigned short* xn2 = (unsigned short*)(ws + 2836480);  // 1,048,576 bf16
    float* xo    = ws + 3360768;      // 1,048,576 floats
    float* h1of  = ws + 4409344;      // bias (1M floats), then h1o bf16 (4M ushorts)
    float* biasb = h1of;
    unsigned short* h1o = (unsigned short*)h1of;
    unsigned short* wp  = (unsigned short*)(ws + 6506496);  // 2,392,064 ushorts
    unsigned short* qwp  = wp;
    unsigned short* owp  = wp + 32768;
    unsigned short* w1p  = wp + 294912;
    unsigned short* w2mp = wp + 1343488;

    hipLaunchKernelGGL(k_wpack, dim3(9408), dim3(256), 0, stream,
                       qw, out_w, mlp_w1, mlp_w2, cpb_w2, wp, w2p);
    hipLaunchKernelGGL(k_qgemm, dim3(256), dim3(256), 0, stream, x, bn1_g, bn1_b, qwp, qt);
    hipLaunchKernelGGL(k_offskv, dim3(1024), dim3(64), 0, stream,
                       qt, off_dw_w, off_dw_b, off_pw_w, x, bn1_g, bn1_b, kw, vw,
                       vgrid, kk, vv);
    hipLaunchKernelGGL(k_cpb, dim3(2048), dim3(256), 0, stream,
                       vgrid, w2p, cpb_w1, cpb_b1, cpb_b2, cpb_w3, cpb_b3, biasb);
    hipLaunchKernelGGL(k_attn, dim3(256), dim3(256), 0, stream, qt, kk, vv, biasb, ao);
    // out projection: M=512, K=512 (BK=128), B=ao bf16, resid=x -> xo + xn2(BN2 bf16)
    k_gemm<3, 512, 128, 8><<<dim3(256), dim3(256), 0, stream>>>(
        owp, ao, x, out_b, xo, xn2, bn2_g, bn2_b);
    // MLP1: M=2048, K=512 (BK=128), B=xn2 bf16, gelu -> h1o bf16
    k_gemm<1, 512, 128, 32><<<dim3(1024), dim3(256), 0, stream>>>(
        w1p, xn2, nullptr, mlp_b1, h1o, nullptr, nullptr, nullptr);
    // MLP2: M=512, K=2048 (BK=128), B=h1o bf16, resid=xo -> d_out
    k_gemm<2, 2048, 128, 8><<<dim3(256), dim3(256), 0, stream>>>(
        w2mp, h1o, xo, mlp_b2, d_out, nullptr, nullptr, nullptr);
}